// Round 10
// baseline (579.239 us; speedup 1.0000x reference)
//
#include <hip/hip_runtime.h>
#include <hip/hip_bf16.h>
#include <math.h>

#define FIN 35
#define FOUT 128
#define NGRAPHS 512
#define NP 5            // feature panels (ceil(35/8))
#define PW 8            // panel width (floats) = 32 B rows
#define STRIP1 32       // nodes per block in nu1
#define STRIP2 16       // nodes per block in nu2
#define CHUNK 8192      // edges per block in hist1/scatter1
#define MAXBUCK 512     // >= ceil(N/256)

// ---------- helpers ----------
__device__ __forceinline__ unsigned int enc_f32(float f) {
    unsigned int u = __float_as_uint(f);
    return (u & 0x80000000u) ? ~u : (u | 0x80000000u);
}
__device__ __forceinline__ float dec_f32(unsigned int u) {
    unsigned int b = (u & 0x80000000u) ? (u ^ 0x80000000u) : ~u;
    return __uint_as_float(b);
}

// ---------- CSR build via two-level LDS radix partition (no global atomics) ----------

__global__ __launch_bounds__(256) void hist1_kernel(const int* __restrict__ dst,
                                                    int* __restrict__ counts,
                                                    int E, int nblk1, int nbuck) {
    __shared__ int h[MAXBUCK];
    for (int t = threadIdx.x; t < nbuck; t += 256) h[t] = 0;
    __syncthreads();
    int base = blockIdx.x * CHUNK;
    int end = min(base + CHUNK, E);
    for (int e = base + threadIdx.x; e < end; e += 256)
        atomicAdd(&h[dst[e] >> 8], 1);
    __syncthreads();
    for (int t = threadIdx.x; t < nbuck; t += 256)
        counts[t * nblk1 + blockIdx.x] = h[t];
}

__global__ void partial_reduce_kernel(const int* __restrict__ v_in, int* __restrict__ partial, int SC) {
    int i = blockIdx.x * 256 + threadIdx.x;
    int v = (i < SC) ? v_in[i] : 0;
    #pragma unroll
    for (int off = 32; off > 0; off >>= 1) v += __shfl_down(v, off, 64);
    __shared__ int w[4];
    if ((threadIdx.x & 63) == 0) w[threadIdx.x >> 6] = v;
    __syncthreads();
    if (threadIdx.x == 0) partial[blockIdx.x] = w[0] + w[1] + w[2] + w[3];
}

__global__ void scan_partials_kernel(int* __restrict__ partial, int NB) {
    __shared__ int lds[1024];
    int t = threadIdx.x;
    int v = (t < NB) ? partial[t] : 0;
    lds[t] = v;
    __syncthreads();
    for (int off = 1; off < 1024; off <<= 1) {
        int tv = (t >= off) ? lds[t - off] : 0;
        __syncthreads();
        lds[t] += tv;
        __syncthreads();
    }
    if (t < NB) partial[t] = lds[t] - v;   // exclusive
}

__global__ void scan_final_kernel(const int* __restrict__ v_in, const int* __restrict__ partial,
                                  int* __restrict__ outx, int SC) {
    __shared__ int lds[256];
    int i = blockIdx.x * 256 + threadIdx.x;
    int v = (i < SC) ? v_in[i] : 0;
    lds[threadIdx.x] = v;
    __syncthreads();
    for (int off = 1; off < 256; off <<= 1) {
        int tv = (threadIdx.x >= off) ? lds[threadIdx.x - off] : 0;
        __syncthreads();
        lds[threadIdx.x] += tv;
        __syncthreads();
    }
    int excl = lds[threadIdx.x] - v + partial[blockIdx.x];
    if (i < SC) {
        outx[i] = excl;
        if (i == SC - 1) outx[SC] = excl + v;
    }
}

__global__ __launch_bounds__(256) void scatter1_kernel(const int* __restrict__ src,
                                                       const int* __restrict__ dst,
                                                       const int* __restrict__ offs,
                                                       int* __restrict__ ebuf,
                                                       int E, int nblk1, int nbuck) {
    __shared__ int cur[MAXBUCK];
    for (int t = threadIdx.x; t < nbuck; t += 256) cur[t] = offs[t * nblk1 + blockIdx.x];
    __syncthreads();
    int base = blockIdx.x * CHUNK;
    int end = min(base + CHUNK, E);
    for (int e = base + threadIdx.x; e < end; e += 256) {
        int d = dst[e];
        int p = atomicAdd(&cur[d >> 8], 1);
        ebuf[p] = (src[e] << 8) | (d & 255);
    }
}

__global__ __launch_bounds__(256) void csr2_kernel(const int* __restrict__ ebuf,
                                                   const int* __restrict__ offs,
                                                   int* __restrict__ row_ptr,
                                                   int* __restrict__ esrc,
                                                   int E, int nblk1, int nbuck, int N) {
    __shared__ int h[256];
    __shared__ int scn[256];
    int b = blockIdx.x;
    int t = threadIdx.x;
    int bstart = offs[b * nblk1];
    int bend = (b + 1 < nbuck) ? offs[(b + 1) * nblk1] : E;

    h[t] = 0;
    __syncthreads();
    for (int k = bstart + t; k < bend; k += 256)
        atomicAdd(&h[ebuf[k] & 255], 1);
    __syncthreads();

    int v = h[t];
    scn[t] = v;
    __syncthreads();
    for (int off = 1; off < 256; off <<= 1) {
        int tv = (t >= off) ? scn[t - off] : 0;
        __syncthreads();
        scn[t] += tv;
        __syncthreads();
    }
    int excl = scn[t] - v;
    int node = (b << 8) + t;
    if (node < N) row_ptr[node] = bstart + excl;
    if (b == 0 && t == 0) row_ptr[N] = E;

    __syncthreads();
    h[t] = bstart + excl;
    __syncthreads();
    for (int k = bstart + t; k < bend; k += 256) {
        int e = ebuf[k];
        int p = atomicAdd(&h[e & 255], 1);
        esrc[p] = e >> 8;
    }
}

// ---------- repack x[N][35] -> 5 panels xp[p][N][8] (32 B rows, pad zeroed) ----------
__global__ void repack_kernel(const float* __restrict__ x, float* __restrict__ xp, int N) {
    int t = blockIdx.x * 256 + threadIdx.x;          // < N*40
    if (t >= N * (NP * PW)) return;
    int n = t / (NP * PW);
    int f = t - n * (NP * PW);
    float v = (f < FIN) ? x[(long long)n * FIN + f] : 0.0f;
    xp[((long long)(f >> 3) * N + n) * PW + (f & 7)] = v;
}

// ---------- XCD-affinity panelized gather, float4 lanes ----------
// Flat work space W = NP*N*2 items (item = one node x one f-quad), pass-major.
// Work share q (of 8) is claimed by blocks with blockIdx%8==q (round-robin block->XCD
// heuristic; locality-only). Each lane loads a float4 => a wave-load instruction spans
// 32 random rows (vs 8 with scalar lanes), 4 accumulator chains keep ~128 row-segments
// in flight per wave: attacks the L2-hit-latency MLP limit.
__global__ __launch_bounds__(256) void gather_panel_kernel(const float* __restrict__ panels,
                                                           const int* __restrict__ row_ptr,
                                                           const int* __restrict__ esrc,
                                                           float* __restrict__ sp,
                                                           int N, int Wtot, int WS) {
    int q = blockIdx.x & 7;
    int m = blockIdx.x >> 3;
    int w = q * WS + m * 256 + threadIdx.x;
    int wend = min((q + 1) * WS, Wtot);
    if (w >= wend) return;
    int NI = N * 2;                  // items per pass
    int pass = w / NI;
    int t = w - pass * NI;
    int n = t >> 1;
    int fb = (t & 1) << 2;           // feature quad base: 0 or 4
    const float* base = panels + (long long)pass * N * PW + fb;
    int b = row_ptr[n];
    int e = row_ptr[n + 1];
    float4 a0 = {0.f,0.f,0.f,0.f}, a1 = {0.f,0.f,0.f,0.f};
    float4 a2 = {0.f,0.f,0.f,0.f}, a3 = {0.f,0.f,0.f,0.f};
    int k = b;
    for (; k + 4 <= e; k += 4) {
        int s0 = esrc[k], s1 = esrc[k + 1], s2 = esrc[k + 2], s3 = esrc[k + 3];
        float4 v0 = *(const float4*)(base + ((long long)s0 << 3));
        float4 v1 = *(const float4*)(base + ((long long)s1 << 3));
        float4 v2 = *(const float4*)(base + ((long long)s2 << 3));
        float4 v3 = *(const float4*)(base + ((long long)s3 << 3));
        a0.x += v0.x; a0.y += v0.y; a0.z += v0.z; a0.w += v0.w;
        a1.x += v1.x; a1.y += v1.y; a1.z += v1.z; a1.w += v1.w;
        a2.x += v2.x; a2.y += v2.y; a2.z += v2.z; a2.w += v2.w;
        a3.x += v3.x; a3.y += v3.y; a3.z += v3.z; a3.w += v3.w;
    }
    for (; k < e; ++k) {
        float4 v0 = *(const float4*)(base + ((long long)esrc[k] << 3));
        a0.x += v0.x; a0.y += v0.y; a0.z += v0.z; a0.w += v0.w;
    }
    float inv = 1.0f / (float)max(e - b, 1);
    float4 r;
    r.x = ((a0.x + a1.x) + (a2.x + a3.x)) * inv;
    r.y = ((a0.y + a1.y) + (a2.y + a3.y)) * inv;
    r.z = ((a0.z + a1.z) + (a2.z + a3.z)) * inv;
    r.w = ((a0.w + a1.w) + (a2.w + a3.w)) * inv;
    *(float4*)(sp + (long long)pass * N * PW + (n << 3) + fb) = r;
}

// ---------- nu1: h1 = relu(agg@Wl1 + bl1 + x@Wr1), all operands LDS-staged; panel output ----------
__global__ __launch_bounds__(256) void nu1_kernel(const float* __restrict__ x,
                                                  const float* __restrict__ s1p,
                                                  const float* __restrict__ Wl,
                                                  const float* __restrict__ bl,
                                                  const float* __restrict__ Wr,
                                                  float* __restrict__ h1p,
                                                  int N) {
    __shared__ float x_sh[STRIP1 * FIN];
    __shared__ float s_sh[STRIP1 * FIN];
    __shared__ float wl_sh[FIN * FIN];
    __shared__ float wr_sh[FIN * FIN];
    __shared__ float bl_sh[FIN];

    int node0 = blockIdx.x * STRIP1;
    if (node0 >= N) return;
    int nn = min(STRIP1, N - node0);
    int tot = nn * FIN;

    for (int t = threadIdx.x; t < FIN * FIN; t += 256) {
        wl_sh[t] = Wl[t];
        wr_sh[t] = Wr[t];
    }
    if (threadIdx.x < FIN) bl_sh[threadIdx.x] = bl[threadIdx.x];
    for (int t = threadIdx.x; t < tot; t += 256) {
        x_sh[t] = x[(long long)node0 * FIN + t];
        int nl = t / FIN;
        int i = t - nl * FIN;
        s_sh[t] = s1p[((long long)(i >> 3) * N + node0 + nl) * PW + (i & 7)];
    }
    __syncthreads();

    for (int t = threadIdx.x; t < tot; t += 256) {
        int nl = t / FIN;
        int j = t - nl * FIN;
        float acc = bl_sh[j];
        #pragma unroll
        for (int i = 0; i < FIN; ++i) {
            acc = fmaf(s_sh[nl * FIN + i], wl_sh[i * FIN + j], acc);
            acc = fmaf(x_sh[nl * FIN + i], wr_sh[i * FIN + j], acc);
        }
        acc = fmaxf(acc, 0.0f);
        h1p[((long long)(j >> 3) * N + node0 + nl) * PW + (j & 7)] = acc;   // panel layout only
    }
}

// ---------- nu2 + pool: h2 = agg@Wl2 + bl2 + h1@Wr2, segment-batched graph max ----------
__global__ __launch_bounds__(128) void nu2_pool_kernel(const float* __restrict__ h1p,
                                                       const float* __restrict__ s2p,
                                                       const float* __restrict__ Wl,
                                                       const float* __restrict__ bl,
                                                       const float* __restrict__ Wr,
                                                       const int* __restrict__ batch,
                                                       unsigned int* __restrict__ genc,
                                                       int N) {
    __shared__ float s_sh[STRIP2 * FIN];
    __shared__ float h_sh[STRIP2 * FIN];
    __shared__ int b_sh[STRIP2];
    int node0 = blockIdx.x * STRIP2;
    if (node0 >= N) return;
    int nn = min(STRIP2, N - node0);
    int tot = nn * FIN;

    for (int t = threadIdx.x; t < tot; t += 128) {
        int nl = t / FIN;
        int i = t - nl * FIN;
        long long pidx = ((long long)(i >> 3) * N + node0 + nl) * PW + (i & 7);
        h_sh[t] = h1p[pidx];
        s_sh[t] = s2p[pidx];
    }
    if (threadIdx.x < nn) b_sh[threadIdx.x] = batch[node0 + threadIdx.x];
    __syncthreads();

    int j = threadIdx.x;
    float wl[FIN], wr[FIN];
    #pragma unroll
    for (int i = 0; i < FIN; ++i) {
        wl[i] = Wl[i * FOUT + j];
        wr[i] = Wr[i * FOUT + j];
    }
    float blj = bl[j];

    int curg = b_sh[0];
    float m = -INFINITY;
    for (int nl = 0; nl < nn; ++nl) {
        float acc = blj;
        #pragma unroll
        for (int i = 0; i < FIN; ++i) {
            acc = fmaf(s_sh[nl * FIN + i], wl[i], acc);
            acc = fmaf(h_sh[nl * FIN + i], wr[i], acc);
        }
        int g = b_sh[nl];   // wave-uniform
        if (g != curg) {
            atomicMax(&genc[curg * FOUT + j], enc_f32(m));
            curg = g;
            m = acc;
        } else {
            m = fmaxf(m, acc);
        }
    }
    atomicMax(&genc[curg * FOUT + j], enc_f32(m));
}

// ---------- head: one block (128 threads) per graph ----------
__global__ void head_kernel(const unsigned int* __restrict__ genc,
                            const float* __restrict__ Wg1, const float* __restrict__ bg1,
                            const float* __restrict__ Wg2, const float* __restrict__ bg2,
                            const float* __restrict__ Wo,  const float* __restrict__ bo,
                            float* __restrict__ out) {
    __shared__ float a[FOUT];
    __shared__ float c[FOUT];
    __shared__ float red[2];
    int g = blockIdx.x;
    int j = threadIdx.x;

    a[j] = dec_f32(genc[g * FOUT + j]);
    __syncthreads();

    float acc = bg1[j];
    #pragma unroll 8
    for (int i = 0; i < FOUT; ++i) acc = fmaf(a[i], Wg1[i * FOUT + j], acc);
    c[j] = fmaxf(acc, 0.0f);
    __syncthreads();

    acc = bg2[j];
    #pragma unroll 8
    for (int i = 0; i < FOUT; ++i) acc = fmaf(c[i], Wg2[i * FOUT + j], acc);
    float t = fmaxf(acc, 0.0f) * Wo[j];

    #pragma unroll
    for (int off = 32; off > 0; off >>= 1) t += __shfl_down(t, off, 64);
    if ((threadIdx.x & 63) == 0) red[threadIdx.x >> 6] = t;
    __syncthreads();
    if (threadIdx.x == 0) out[g] = red[0] + red[1] + bo[0];
}

// ---------- launch ----------
extern "C" void kernel_launch(void* const* d_in, const int* in_sizes, int n_in,
                              void* d_out, int out_size, void* d_ws, size_t ws_size,
                              hipStream_t stream) {
    const float* x    = (const float*)d_in[0];
    const int*   ei   = (const int*)  d_in[1];
    const int*   batch= (const int*)  d_in[2];
    const float* Wl1  = (const float*)d_in[3];
    const float* bl1  = (const float*)d_in[4];
    const float* Wr1  = (const float*)d_in[5];
    const float* Wl2  = (const float*)d_in[6];
    const float* bl2  = (const float*)d_in[7];
    const float* Wr2  = (const float*)d_in[8];
    const float* Wg1  = (const float*)d_in[9];
    const float* bg1  = (const float*)d_in[10];
    const float* Wg2  = (const float*)d_in[11];
    const float* bg2  = (const float*)d_in[12];
    const float* Wo   = (const float*)d_in[13];
    const float* bo   = (const float*)d_in[14];
    float* out = (float*)d_out;

    const int N = in_sizes[0] / FIN;
    const int E = in_sizes[1] / 2;
    const int* src = ei;
    const int* dst = ei + E;

    const int nblk1 = (E + CHUNK - 1) / CHUNK;          // 391
    const int nbuck = (N + 255) >> 8;                   // 391 (<= MAXBUCK)
    const int SC = nbuck * nblk1;                       // 152881
    const int NB2 = (SC + 255) / 256;                   // 598 (<= 1024)

    const size_t panel_elems = (size_t)NP * N * PW;     // 4M floats = 16 MB

    // workspace layout (regionA: ebuf early, h1p later — lifetimes disjoint)
    char* ws = (char*)d_ws;
    size_t off = 0;
    auto alloc = [&](size_t bytes) { char* p = ws + off; off += (bytes + 255) & ~255ull; return p; };
    int*          counts  = (int*)alloc((size_t)SC * 4);
    int*          offs    = (int*)alloc((size_t)(SC + 1) * 4);
    int*          partial = (int*)alloc(1024 * 4);
    int*          row_ptr = (int*)alloc((size_t)(N + 1) * 4);
    int*          esrc    = (int*)alloc((size_t)E * 4);
    char*         regionA = (char*)alloc(panel_elems * 4);       // ebuf (12.8 MB) then h1p (16 MB)
    float*        xp_s2p  = (float*)alloc(panel_elems * 4);      // xp (conv1 in) then s2p (conv2 out)
    float*        s1p     = (float*)alloc(panel_elems * 4);
    unsigned int* genc    = (unsigned int*)alloc((size_t)NGRAPHS * FOUT * 4);
    int*   ebuf = (int*)regionA;
    float* h1p  = (float*)regionA;
    (void)ws_size; (void)n_in; (void)out_size;

    const int BS = 256;
    const int Wtot = NP * N * 2;                         // 10*N items (node x f-quad)
    const int WS = (Wtot + 7) / 8;                       // per-XCD work share
    const int bpx = (WS + BS - 1) / BS;                  // blocks per XCD share
    const int rpb = (N * NP * PW + BS - 1) / BS;         // repack blocks
    int nu1b = (N + STRIP1 - 1) / STRIP1;
    int nu2b = (N + STRIP2 - 1) / STRIP2;

    // ---- CSR build (LDS radix, no global atomics; reused by both conv layers) ----
    hipLaunchKernelGGL(hist1_kernel, dim3(nblk1), dim3(BS), 0, stream, dst, counts, E, nblk1, nbuck);
    hipLaunchKernelGGL(partial_reduce_kernel, dim3(NB2), dim3(BS), 0, stream, counts, partial, SC);
    hipLaunchKernelGGL(scan_partials_kernel, dim3(1), dim3(1024), 0, stream, partial, NB2);
    hipLaunchKernelGGL(scan_final_kernel, dim3(NB2), dim3(BS), 0, stream, counts, partial, offs, SC);
    hipLaunchKernelGGL(scatter1_kernel, dim3(nblk1), dim3(BS), 0, stream, src, dst, offs, ebuf, E, nblk1, nbuck);
    hipLaunchKernelGGL(csr2_kernel, dim3(nbuck), dim3(BS), 0, stream, ebuf, offs, row_ptr, esrc, E, nblk1, nbuck, N);

    // ---- conv1: repack -> XCD-affinity float4 panel gather -> LDS node update ----
    hipLaunchKernelGGL(repack_kernel, dim3(rpb), dim3(BS), 0, stream, x, xp_s2p, N);
    hipLaunchKernelGGL(gather_panel_kernel, dim3(8 * bpx), dim3(BS), 0, stream,
                       xp_s2p, row_ptr, esrc, s1p, N, Wtot, WS);
    hipLaunchKernelGGL(nu1_kernel, dim3(nu1b), dim3(BS), 0, stream,
                       x, s1p, Wl1, bl1, Wr1, h1p, N);

    // ---- conv2: XCD-affinity float4 panel gather over h1p -> node update + pool ----
    hipLaunchKernelGGL(gather_panel_kernel, dim3(8 * bpx), dim3(BS), 0, stream,
                       h1p, row_ptr, esrc, xp_s2p, N, Wtot, WS);
    hipMemsetAsync(genc, 0, (size_t)NGRAPHS * FOUT * 4, stream);
    hipLaunchKernelGGL(nu2_pool_kernel, dim3(nu2b), dim3(128), 0, stream,
                       h1p, xp_s2p, Wl2, bl2, Wr2, batch, genc, N);

    // ---- head ----
    hipLaunchKernelGGL(head_kernel, dim3(NGRAPHS), dim3(FOUT), 0, stream,
                       genc, Wg1, bg1, Wg2, bg2, Wo, bo, out);
}

// Round 11
// 494.340 us; speedup vs baseline: 1.1717x; 1.1717x over previous
//
#include <hip/hip_runtime.h>
#include <hip/hip_bf16.h>
#include <math.h>

#define FIN 35
#define FOUT 128
#define NGRAPHS 512
#define NP 5            // feature panels (ceil(35/8))
#define PW 8            // panel width (floats) = 32 B rows
#define STRIP1 32       // nodes per block in nu1
#define STRIP2 16       // nodes per block in nu2
#define CHUNK 8192      // edges per block in hist1/scatter1
#define MAXBUCK 512     // >= ceil(N/256)
#define MAXBE 12288     // csr2 LDS edge-staging capacity (48 KB)

// ---------- helpers ----------
__device__ __forceinline__ unsigned int enc_f32(float f) {
    unsigned int u = __float_as_uint(f);
    return (u & 0x80000000u) ? ~u : (u | 0x80000000u);
}
__device__ __forceinline__ float dec_f32(unsigned int u) {
    unsigned int b = (u & 0x80000000u) ? (u ^ 0x80000000u) : ~u;
    return __uint_as_float(b);
}

// ---------- CSR build via two-level LDS radix partition (no global atomics) ----------

__global__ __launch_bounds__(256) void hist1_kernel(const int* __restrict__ dst,
                                                    int* __restrict__ counts,
                                                    int E, int nblk1, int nbuck) {
    __shared__ int h[MAXBUCK];
    for (int t = threadIdx.x; t < nbuck; t += 256) h[t] = 0;
    __syncthreads();
    int base = blockIdx.x * CHUNK;
    int end = min(base + CHUNK, E);
    for (int e = base + threadIdx.x; e < end; e += 256)
        atomicAdd(&h[dst[e] >> 8], 1);
    __syncthreads();
    for (int t = threadIdx.x; t < nbuck; t += 256)
        counts[t * nblk1 + blockIdx.x] = h[t];
}

__global__ void partial_reduce_kernel(const int* __restrict__ v_in, int* __restrict__ partial, int SC) {
    int i = blockIdx.x * 256 + threadIdx.x;
    int v = (i < SC) ? v_in[i] : 0;
    #pragma unroll
    for (int off = 32; off > 0; off >>= 1) v += __shfl_down(v, off, 64);
    __shared__ int w[4];
    if ((threadIdx.x & 63) == 0) w[threadIdx.x >> 6] = v;
    __syncthreads();
    if (threadIdx.x == 0) partial[blockIdx.x] = w[0] + w[1] + w[2] + w[3];
}

__global__ void scan_partials_kernel(int* __restrict__ partial, int NB) {
    __shared__ int lds[1024];
    int t = threadIdx.x;
    int v = (t < NB) ? partial[t] : 0;
    lds[t] = v;
    __syncthreads();
    for (int off = 1; off < 1024; off <<= 1) {
        int tv = (t >= off) ? lds[t - off] : 0;
        __syncthreads();
        lds[t] += tv;
        __syncthreads();
    }
    if (t < NB) partial[t] = lds[t] - v;   // exclusive
}

__global__ void scan_final_kernel(const int* __restrict__ v_in, const int* __restrict__ partial,
                                  int* __restrict__ outx, int SC) {
    __shared__ int lds[256];
    int i = blockIdx.x * 256 + threadIdx.x;
    int v = (i < SC) ? v_in[i] : 0;
    lds[threadIdx.x] = v;
    __syncthreads();
    for (int off = 1; off < 256; off <<= 1) {
        int tv = (threadIdx.x >= off) ? lds[threadIdx.x - off] : 0;
        __syncthreads();
        lds[threadIdx.x] += tv;
        __syncthreads();
    }
    int excl = lds[threadIdx.x] - v + partial[blockIdx.x];
    if (i < SC) {
        outx[i] = excl;
        if (i == SC - 1) outx[SC] = excl + v;
    }
}

__global__ __launch_bounds__(256) void scatter1_kernel(const int* __restrict__ src,
                                                       const int* __restrict__ dst,
                                                       const int* __restrict__ offs,
                                                       int* __restrict__ ebuf,
                                                       int E, int nblk1, int nbuck) {
    __shared__ int cur[MAXBUCK];
    for (int t = threadIdx.x; t < nbuck; t += 256) cur[t] = offs[t * nblk1 + blockIdx.x];
    __syncthreads();
    int base = blockIdx.x * CHUNK;
    int end = min(base + CHUNK, E);
    for (int e = base + threadIdx.x; e < end; e += 256) {
        int d = dst[e];
        int p = atomicAdd(&cur[d >> 8], 1);
        ebuf[p] = (src[e] << 8) | (d & 255);
    }
}

// Level-2: one block per bucket; bucket edges staged in LDS (skips the ebuf re-read).
__global__ __launch_bounds__(256) void csr2_kernel(const int* __restrict__ ebuf,
                                                   const int* __restrict__ offs,
                                                   int* __restrict__ row_ptr,
                                                   int* __restrict__ esrc,
                                                   int E, int nblk1, int nbuck, int N) {
    __shared__ int h[256];
    __shared__ int scn[256];
    __shared__ int e_sh[MAXBE];
    int b = blockIdx.x;
    int t = threadIdx.x;
    int bstart = offs[b * nblk1];
    int bend = (b + 1 < nbuck) ? offs[(b + 1) * nblk1] : E;
    int cnt = bend - bstart;
    bool fit = (cnt <= MAXBE);

    if (fit)
        for (int k = t; k < cnt; k += 256) e_sh[k] = ebuf[bstart + k];
    h[t] = 0;
    __syncthreads();
    for (int k = t; k < cnt; k += 256)
        atomicAdd(&h[(fit ? e_sh[k] : ebuf[bstart + k]) & 255], 1);
    __syncthreads();

    int v = h[t];
    scn[t] = v;
    __syncthreads();
    for (int off = 1; off < 256; off <<= 1) {
        int tv = (t >= off) ? scn[t - off] : 0;
        __syncthreads();
        scn[t] += tv;
        __syncthreads();
    }
    int excl = scn[t] - v;
    int node = (b << 8) + t;
    if (node < N) row_ptr[node] = bstart + excl;
    if (b == 0 && t == 0) row_ptr[N] = E;

    __syncthreads();
    h[t] = bstart + excl;
    __syncthreads();
    for (int k = t; k < cnt; k += 256) {
        int e = fit ? e_sh[k] : ebuf[bstart + k];
        int p = atomicAdd(&h[e & 255], 1);
        esrc[p] = e >> 8;
    }
}

// ---------- repack x[N][35] -> 5 panels xp[p][N][8] (32 B rows, pad zeroed) ----------
__global__ void repack_kernel(const float* __restrict__ x, float* __restrict__ xp, int N) {
    int t = blockIdx.x * 256 + threadIdx.x;          // < N*40
    if (t >= N * (NP * PW)) return;
    int n = t / (NP * PW);
    int f = t - n * (NP * PW);
    float v = (f < FIN) ? x[(long long)n * FIN + f] : 0.0f;
    xp[((long long)(f >> 3) * N + n) * PW + (f & 7)] = v;
}

// ---------- XCD-affinity panelized gather (scalar lanes, 8 chains) ----------
// Flat work space W = NP*N*PW items, pass-major; share q of 8 claimed by blocks with
// blockIdx%8==q (round-robin block->XCD; locality-only heuristic). 1954 blocks/share vs
// ~256 resident keeps a sliding ~13% window -> passes serialize, one ~3.2 MB panel
// L2-resident per XCD at a time (round 9: FETCH 99 MB). 8 independent accumulator
// chains double the outstanding row-segments per wave vs round 9 (MLP attack).
__global__ __launch_bounds__(256) void gather_panel_kernel(const float* __restrict__ panels,
                                                           const int* __restrict__ row_ptr,
                                                           const int* __restrict__ esrc,
                                                           float* __restrict__ sp,
                                                           int N, int WS) {
    int q = blockIdx.x & 7;
    int m = blockIdx.x >> 3;
    int w = q * WS + m * 256 + threadIdx.x;          // W = 40*N fits int
    if (w >= (q + 1) * WS) return;
    int NPW = N * PW;
    int pass = w / NPW;
    int t = w - pass * NPW;
    int n = t >> 3;
    int f = t & 7;
    const float* srcf = panels + (long long)pass * NPW + f;
    int b = row_ptr[n];
    int e = row_ptr[n + 1];
    float a0 = 0.0f, a1 = 0.0f, a2 = 0.0f, a3 = 0.0f;
    float a4 = 0.0f, a5 = 0.0f, a6 = 0.0f, a7 = 0.0f;
    int k = b;
    for (; k + 8 <= e; k += 8) {
        int s0 = esrc[k],     s1 = esrc[k + 1], s2 = esrc[k + 2], s3 = esrc[k + 3];
        int s4 = esrc[k + 4], s5 = esrc[k + 5], s6 = esrc[k + 6], s7 = esrc[k + 7];
        a0 += srcf[s0 << 3];
        a1 += srcf[s1 << 3];
        a2 += srcf[s2 << 3];
        a3 += srcf[s3 << 3];
        a4 += srcf[s4 << 3];
        a5 += srcf[s5 << 3];
        a6 += srcf[s6 << 3];
        a7 += srcf[s7 << 3];
    }
    for (; k < e; ++k) a0 += srcf[esrc[k] << 3];
    float acc = ((a0 + a1) + (a2 + a3)) + ((a4 + a5) + (a6 + a7));
    sp[(long long)pass * NPW + t] = acc / (float)max(e - b, 1);
}

// ---------- nu1: h1 = relu(agg@Wl1 + bl1 + x@Wr1), all operands LDS-staged; panel output ----------
__global__ __launch_bounds__(256) void nu1_kernel(const float* __restrict__ x,
                                                  const float* __restrict__ s1p,
                                                  const float* __restrict__ Wl,
                                                  const float* __restrict__ bl,
                                                  const float* __restrict__ Wr,
                                                  float* __restrict__ h1p,
                                                  int N) {
    __shared__ float x_sh[STRIP1 * FIN];
    __shared__ float s_sh[STRIP1 * FIN];
    __shared__ float wl_sh[FIN * FIN];
    __shared__ float wr_sh[FIN * FIN];
    __shared__ float bl_sh[FIN];

    int node0 = blockIdx.x * STRIP1;
    if (node0 >= N) return;
    int nn = min(STRIP1, N - node0);
    int tot = nn * FIN;

    for (int t = threadIdx.x; t < FIN * FIN; t += 256) {
        wl_sh[t] = Wl[t];
        wr_sh[t] = Wr[t];
    }
    if (threadIdx.x < FIN) bl_sh[threadIdx.x] = bl[threadIdx.x];
    for (int t = threadIdx.x; t < tot; t += 256) {
        x_sh[t] = x[(long long)node0 * FIN + t];
        int nl = t / FIN;
        int i = t - nl * FIN;
        s_sh[t] = s1p[((long long)(i >> 3) * N + node0 + nl) * PW + (i & 7)];
    }
    __syncthreads();

    for (int t = threadIdx.x; t < tot; t += 256) {
        int nl = t / FIN;
        int j = t - nl * FIN;
        float acc = bl_sh[j];
        #pragma unroll
        for (int i = 0; i < FIN; ++i) {
            acc = fmaf(s_sh[nl * FIN + i], wl_sh[i * FIN + j], acc);
            acc = fmaf(x_sh[nl * FIN + i], wr_sh[i * FIN + j], acc);
        }
        acc = fmaxf(acc, 0.0f);
        h1p[((long long)(j >> 3) * N + node0 + nl) * PW + (j & 7)] = acc;   // panel layout only
    }
}

// ---------- nu2 + pool: h2 = agg@Wl2 + bl2 + h1@Wr2, segment-batched graph max ----------
__global__ __launch_bounds__(128) void nu2_pool_kernel(const float* __restrict__ h1p,
                                                       const float* __restrict__ s2p,
                                                       const float* __restrict__ Wl,
                                                       const float* __restrict__ bl,
                                                       const float* __restrict__ Wr,
                                                       const int* __restrict__ batch,
                                                       unsigned int* __restrict__ genc,
                                                       int N) {
    __shared__ float s_sh[STRIP2 * FIN];
    __shared__ float h_sh[STRIP2 * FIN];
    __shared__ int b_sh[STRIP2];
    int node0 = blockIdx.x * STRIP2;
    if (node0 >= N) return;
    int nn = min(STRIP2, N - node0);
    int tot = nn * FIN;

    for (int t = threadIdx.x; t < tot; t += 128) {
        int nl = t / FIN;
        int i = t - nl * FIN;
        long long pidx = ((long long)(i >> 3) * N + node0 + nl) * PW + (i & 7);
        h_sh[t] = h1p[pidx];
        s_sh[t] = s2p[pidx];
    }
    if (threadIdx.x < nn) b_sh[threadIdx.x] = batch[node0 + threadIdx.x];
    __syncthreads();

    int j = threadIdx.x;
    float wl[FIN], wr[FIN];
    #pragma unroll
    for (int i = 0; i < FIN; ++i) {
        wl[i] = Wl[i * FOUT + j];
        wr[i] = Wr[i * FOUT + j];
    }
    float blj = bl[j];

    int curg = b_sh[0];
    float m = -INFINITY;
    for (int nl = 0; nl < nn; ++nl) {
        float acc = blj;
        #pragma unroll
        for (int i = 0; i < FIN; ++i) {
            acc = fmaf(s_sh[nl * FIN + i], wl[i], acc);
            acc = fmaf(h_sh[nl * FIN + i], wr[i], acc);
        }
        int g = b_sh[nl];   // wave-uniform
        if (g != curg) {
            atomicMax(&genc[curg * FOUT + j], enc_f32(m));
            curg = g;
            m = acc;
        } else {
            m = fmaxf(m, acc);
        }
    }
    atomicMax(&genc[curg * FOUT + j], enc_f32(m));
}

// ---------- head: one block (128 threads) per graph ----------
__global__ void head_kernel(const unsigned int* __restrict__ genc,
                            const float* __restrict__ Wg1, const float* __restrict__ bg1,
                            const float* __restrict__ Wg2, const float* __restrict__ bg2,
                            const float* __restrict__ Wo,  const float* __restrict__ bo,
                            float* __restrict__ out) {
    __shared__ float a[FOUT];
    __shared__ float c[FOUT];
    __shared__ float red[2];
    int g = blockIdx.x;
    int j = threadIdx.x;

    a[j] = dec_f32(genc[g * FOUT + j]);
    __syncthreads();

    float acc = bg1[j];
    #pragma unroll 8
    for (int i = 0; i < FOUT; ++i) acc = fmaf(a[i], Wg1[i * FOUT + j], acc);
    c[j] = fmaxf(acc, 0.0f);
    __syncthreads();

    acc = bg2[j];
    #pragma unroll 8
    for (int i = 0; i < FOUT; ++i) acc = fmaf(c[i], Wg2[i * FOUT + j], acc);
    float t = fmaxf(acc, 0.0f) * Wo[j];

    #pragma unroll
    for (int off = 32; off > 0; off >>= 1) t += __shfl_down(t, off, 64);
    if ((threadIdx.x & 63) == 0) red[threadIdx.x >> 6] = t;
    __syncthreads();
    if (threadIdx.x == 0) out[g] = red[0] + red[1] + bo[0];
}

// ---------- launch ----------
extern "C" void kernel_launch(void* const* d_in, const int* in_sizes, int n_in,
                              void* d_out, int out_size, void* d_ws, size_t ws_size,
                              hipStream_t stream) {
    const float* x    = (const float*)d_in[0];
    const int*   ei   = (const int*)  d_in[1];
    const int*   batch= (const int*)  d_in[2];
    const float* Wl1  = (const float*)d_in[3];
    const float* bl1  = (const float*)d_in[4];
    const float* Wr1  = (const float*)d_in[5];
    const float* Wl2  = (const float*)d_in[6];
    const float* bl2  = (const float*)d_in[7];
    const float* Wr2  = (const float*)d_in[8];
    const float* Wg1  = (const float*)d_in[9];
    const float* bg1  = (const float*)d_in[10];
    const float* Wg2  = (const float*)d_in[11];
    const float* bg2  = (const float*)d_in[12];
    const float* Wo   = (const float*)d_in[13];
    const float* bo   = (const float*)d_in[14];
    float* out = (float*)d_out;

    const int N = in_sizes[0] / FIN;
    const int E = in_sizes[1] / 2;
    const int* src = ei;
    const int* dst = ei + E;

    const int nblk1 = (E + CHUNK - 1) / CHUNK;          // 391
    const int nbuck = (N + 255) >> 8;                   // 391 (<= MAXBUCK)
    const int SC = nbuck * nblk1;                       // 152881
    const int NB2 = (SC + 255) / 256;                   // 598 (<= 1024)

    const size_t panel_elems = (size_t)NP * N * PW;     // 4M floats = 16 MB

    // workspace layout (regionA: ebuf early, h1p later — lifetimes disjoint)
    char* ws = (char*)d_ws;
    size_t off = 0;
    auto alloc = [&](size_t bytes) { char* p = ws + off; off += (bytes + 255) & ~255ull; return p; };
    int*          counts  = (int*)alloc((size_t)SC * 4);
    int*          offs    = (int*)alloc((size_t)(SC + 1) * 4);
    int*          partial = (int*)alloc(1024 * 4);
    int*          row_ptr = (int*)alloc((size_t)(N + 1) * 4);
    int*          esrc    = (int*)alloc((size_t)E * 4);
    char*         regionA = (char*)alloc(panel_elems * 4);       // ebuf (12.8 MB) then h1p (16 MB)
    float*        xp_s2p  = (float*)alloc(panel_elems * 4);      // xp (conv1 in) then s2p (conv2 out)
    float*        s1p     = (float*)alloc(panel_elems * 4);
    unsigned int* genc    = (unsigned int*)alloc((size_t)NGRAPHS * FOUT * 4);
    int*   ebuf = (int*)regionA;
    float* h1p  = (float*)regionA;
    (void)ws_size; (void)n_in; (void)out_size;

    const int BS = 256;
    const int Wtot = NP * N * PW;                        // 40*N, divisible by 8
    const int WS = Wtot / 8;                             // per-XCD work share (5*N)
    const int bpx = (WS + BS - 1) / BS;                  // blocks per XCD share (1954)
    const int rpb = (N * NP * PW + BS - 1) / BS;         // repack blocks
    int nu1b = (N + STRIP1 - 1) / STRIP1;
    int nu2b = (N + STRIP2 - 1) / STRIP2;

    // ---- CSR build (LDS radix, no global atomics; reused by both conv layers) ----
    hipLaunchKernelGGL(hist1_kernel, dim3(nblk1), dim3(BS), 0, stream, dst, counts, E, nblk1, nbuck);
    hipLaunchKernelGGL(partial_reduce_kernel, dim3(NB2), dim3(BS), 0, stream, counts, partial, SC);
    hipLaunchKernelGGL(scan_partials_kernel, dim3(1), dim3(1024), 0, stream, partial, NB2);
    hipLaunchKernelGGL(scan_final_kernel, dim3(NB2), dim3(BS), 0, stream, counts, partial, offs, SC);
    hipLaunchKernelGGL(scatter1_kernel, dim3(nblk1), dim3(BS), 0, stream, src, dst, offs, ebuf, E, nblk1, nbuck);
    hipLaunchKernelGGL(csr2_kernel, dim3(nbuck), dim3(BS), 0, stream, ebuf, offs, row_ptr, esrc, E, nblk1, nbuck, N);

    // ---- conv1: repack -> XCD-affinity panel gather -> LDS node update ----
    hipLaunchKernelGGL(repack_kernel, dim3(rpb), dim3(BS), 0, stream, x, xp_s2p, N);
    hipLaunchKernelGGL(gather_panel_kernel, dim3(8 * bpx), dim3(BS), 0, stream,
                       xp_s2p, row_ptr, esrc, s1p, N, WS);
    hipLaunchKernelGGL(nu1_kernel, dim3(nu1b), dim3(BS), 0, stream,
                       x, s1p, Wl1, bl1, Wr1, h1p, N);

    // ---- conv2: XCD-affinity panel gather over h1p -> node update + pool ----
    hipLaunchKernelGGL(gather_panel_kernel, dim3(8 * bpx), dim3(BS), 0, stream,
                       h1p, row_ptr, esrc, xp_s2p, N, WS);
    hipMemsetAsync(genc, 0, (size_t)NGRAPHS * FOUT * 4, stream);
    hipLaunchKernelGGL(nu2_pool_kernel, dim3(nu2b), dim3(128), 0, stream,
                       h1p, xp_s2p, Wl2, bl2, Wr2, batch, genc, N);

    // ---- head ----
    hipLaunchKernelGGL(head_kernel, dim3(NGRAPHS), dim3(FOUT), 0, stream,
                       genc, Wg1, bg1, Wg2, bg2, Wo, bo, out);
}

// Round 12
// 471.336 us; speedup vs baseline: 1.2289x; 1.0488x over previous
//
#include <hip/hip_runtime.h>
#include <hip/hip_bf16.h>
#include <math.h>

#define FIN 35
#define FOUT 128
#define NGRAPHS 512
#define NP 5            // feature panels (ceil(35/8))
#define PW 8            // panel width (floats) = 32 B rows
#define STRIP1 32       // nodes per block in nu1
#define STRIP2 16       // nodes per block in nu2
#define CHUNK 8192      // edges per block in hist1/scatter1
#define MAXBUCK 512     // >= ceil(N/256)
#define MAXBE 12288     // csr2 LDS edge-staging capacity (48 KB)

// ---------- helpers ----------
__device__ __forceinline__ unsigned int enc_f32(float f) {
    unsigned int u = __float_as_uint(f);
    return (u & 0x80000000u) ? ~u : (u | 0x80000000u);
}
__device__ __forceinline__ float dec_f32(unsigned int u) {
    unsigned int b = (u & 0x80000000u) ? (u ^ 0x80000000u) : ~u;
    return __uint_as_float(b);
}

// ---------- CSR build via two-level LDS radix partition (no global atomics) ----------

__global__ __launch_bounds__(256) void hist1_kernel(const int* __restrict__ dst,
                                                    int* __restrict__ counts,
                                                    int E, int nblk1, int nbuck) {
    __shared__ int h[MAXBUCK];
    for (int t = threadIdx.x; t < nbuck; t += 256) h[t] = 0;
    __syncthreads();
    int base = blockIdx.x * CHUNK;
    int end = min(base + CHUNK, E);
    for (int e = base + threadIdx.x; e < end; e += 256)
        atomicAdd(&h[dst[e] >> 8], 1);
    __syncthreads();
    for (int t = threadIdx.x; t < nbuck; t += 256)
        counts[t * nblk1 + blockIdx.x] = h[t];
}

__global__ void partial_reduce_kernel(const int* __restrict__ v_in, int* __restrict__ partial, int SC) {
    int i = blockIdx.x * 256 + threadIdx.x;
    int v = (i < SC) ? v_in[i] : 0;
    #pragma unroll
    for (int off = 32; off > 0; off >>= 1) v += __shfl_down(v, off, 64);
    __shared__ int w[4];
    if ((threadIdx.x & 63) == 0) w[threadIdx.x >> 6] = v;
    __syncthreads();
    if (threadIdx.x == 0) partial[blockIdx.x] = w[0] + w[1] + w[2] + w[3];
}

__global__ void scan_partials_kernel(int* __restrict__ partial, int NB) {
    __shared__ int lds[1024];
    int t = threadIdx.x;
    int v = (t < NB) ? partial[t] : 0;
    lds[t] = v;
    __syncthreads();
    for (int off = 1; off < 1024; off <<= 1) {
        int tv = (t >= off) ? lds[t - off] : 0;
        __syncthreads();
        lds[t] += tv;
        __syncthreads();
    }
    if (t < NB) partial[t] = lds[t] - v;   // exclusive
}

__global__ void scan_final_kernel(const int* __restrict__ v_in, const int* __restrict__ partial,
                                  int* __restrict__ outx, int SC) {
    __shared__ int lds[256];
    int i = blockIdx.x * 256 + threadIdx.x;
    int v = (i < SC) ? v_in[i] : 0;
    lds[threadIdx.x] = v;
    __syncthreads();
    for (int off = 1; off < 256; off <<= 1) {
        int tv = (threadIdx.x >= off) ? lds[threadIdx.x - off] : 0;
        __syncthreads();
        lds[threadIdx.x] += tv;
        __syncthreads();
    }
    int excl = lds[threadIdx.x] - v + partial[blockIdx.x];
    if (i < SC) {
        outx[i] = excl;
        if (i == SC - 1) outx[SC] = excl + v;
    }
}

__global__ __launch_bounds__(256) void scatter1_kernel(const int* __restrict__ src,
                                                       const int* __restrict__ dst,
                                                       const int* __restrict__ offs,
                                                       int* __restrict__ ebuf,
                                                       int E, int nblk1, int nbuck) {
    __shared__ int cur[MAXBUCK];
    for (int t = threadIdx.x; t < nbuck; t += 256) cur[t] = offs[t * nblk1 + blockIdx.x];
    __syncthreads();
    int base = blockIdx.x * CHUNK;
    int end = min(base + CHUNK, E);
    for (int e = base + threadIdx.x; e < end; e += 256) {
        int d = dst[e];
        int p = atomicAdd(&cur[d >> 8], 1);
        ebuf[p] = (src[e] << 8) | (d & 255);
    }
}

// Level-2: one block per bucket; bucket edges staged in LDS (skips the ebuf re-read).
__global__ __launch_bounds__(256) void csr2_kernel(const int* __restrict__ ebuf,
                                                   const int* __restrict__ offs,
                                                   int* __restrict__ row_ptr,
                                                   int* __restrict__ esrc,
                                                   int E, int nblk1, int nbuck, int N) {
    __shared__ int h[256];
    __shared__ int scn[256];
    __shared__ int e_sh[MAXBE];
    int b = blockIdx.x;
    int t = threadIdx.x;
    int bstart = offs[b * nblk1];
    int bend = (b + 1 < nbuck) ? offs[(b + 1) * nblk1] : E;
    int cnt = bend - bstart;
    bool fit = (cnt <= MAXBE);

    if (fit)
        for (int k = t; k < cnt; k += 256) e_sh[k] = ebuf[bstart + k];
    h[t] = 0;
    __syncthreads();
    for (int k = t; k < cnt; k += 256)
        atomicAdd(&h[(fit ? e_sh[k] : ebuf[bstart + k]) & 255], 1);
    __syncthreads();

    int v = h[t];
    scn[t] = v;
    __syncthreads();
    for (int off = 1; off < 256; off <<= 1) {
        int tv = (t >= off) ? scn[t - off] : 0;
        __syncthreads();
        scn[t] += tv;
        __syncthreads();
    }
    int excl = scn[t] - v;
    int node = (b << 8) + t;
    if (node < N) row_ptr[node] = bstart + excl;
    if (b == 0 && t == 0) row_ptr[N] = E;

    __syncthreads();
    h[t] = bstart + excl;
    __syncthreads();
    for (int k = t; k < cnt; k += 256) {
        int e = fit ? e_sh[k] : ebuf[bstart + k];
        int p = atomicAdd(&h[e & 255], 1);
        esrc[p] = e >> 8;
    }
}

// ---------- repack x[N][35] -> 5 panels xp[p][N][8] (32 B rows, pad zeroed) ----------
__global__ void repack_kernel(const float* __restrict__ x, float* __restrict__ xp, int N) {
    int t = blockIdx.x * 256 + threadIdx.x;          // < N*40
    if (t >= N * (NP * PW)) return;
    int n = t / (NP * PW);
    int f = t - n * (NP * PW);
    float v = (f < FIN) ? x[(long long)n * FIN + f] : 0.0f;
    xp[((long long)(f >> 3) * N + n) * PW + (f & 7)] = v;
}

// ---------- XCD-affinity panelized gather: float4 lanes + 4-way edge split ----------
// Item = (node, quad, q4): 8 items/node/pass -> Wtot = 40N (same thread count as the
// proven-clean scalar mapping: resident window ~6% of an XCD share, passes serialize,
// one ~3.2 MB panel L2-resident per XCD). Each lane loads float4 (2 lanes per 32 B row)
// and covers 1/4 of its node's edge list; 2 shfl_xor rounds (lane bits 0-1) combine the
// 4 partials. Wave-load instructions per edge drop 4x vs scalar lanes (TA-bound fix).
// WS is 256-aligned and Wtot is 8-aligned, so shfl groups never straddle an early return.
__global__ __launch_bounds__(256) void gather_panel_kernel(const float* __restrict__ panels,
                                                           const int* __restrict__ row_ptr,
                                                           const int* __restrict__ esrc,
                                                           float* __restrict__ sp,
                                                           int N, int Wtot, int WS) {
    int q = blockIdx.x & 7;
    int m = blockIdx.x >> 3;
    int w = q * WS + m * 256 + threadIdx.x;
    int wend = min((q + 1) * WS, Wtot);
    if (w >= wend) return;                   // cut is 8-aligned (Wtot=40N, WS%256==0)
    int NI = N * 8;                          // items per pass
    int pass = w / NI;
    int t = w - pass * NI;
    int n = t >> 3;
    int quad = (t >> 2) & 1;                 // == (threadIdx>>2)&1
    int q4 = t & 3;                          // == threadIdx&3
    const float* base = panels + (long long)pass * N * PW + (quad << 2);
    int b = row_ptr[n];
    int e = row_ptr[n + 1];
    int deg = e - b;
    int k0 = b + ((deg * q4) >> 2);
    int k1 = b + ((deg * (q4 + 1)) >> 2);

    float4 A0 = {0.f,0.f,0.f,0.f}, A1 = {0.f,0.f,0.f,0.f};
    float4 A2 = {0.f,0.f,0.f,0.f}, A3 = {0.f,0.f,0.f,0.f};
    int k = k0;
    for (; k + 4 <= k1; k += 4) {
        int s0 = esrc[k], s1 = esrc[k + 1], s2 = esrc[k + 2], s3 = esrc[k + 3];
        float4 v0 = *(const float4*)(base + (s0 << 3));
        float4 v1 = *(const float4*)(base + (s1 << 3));
        float4 v2 = *(const float4*)(base + (s2 << 3));
        float4 v3 = *(const float4*)(base + (s3 << 3));
        A0.x += v0.x; A0.y += v0.y; A0.z += v0.z; A0.w += v0.w;
        A1.x += v1.x; A1.y += v1.y; A1.z += v1.z; A1.w += v1.w;
        A2.x += v2.x; A2.y += v2.y; A2.z += v2.z; A2.w += v2.w;
        A3.x += v3.x; A3.y += v3.y; A3.z += v3.z; A3.w += v3.w;
    }
    for (; k < k1; ++k) {
        float4 v0 = *(const float4*)(base + (esrc[k] << 3));
        A0.x += v0.x; A0.y += v0.y; A0.z += v0.z; A0.w += v0.w;
    }
    float sx = (A0.x + A1.x) + (A2.x + A3.x);
    float sy = (A0.y + A1.y) + (A2.y + A3.y);
    float sz = (A0.z + A1.z) + (A2.z + A3.z);
    float sw = (A0.w + A1.w) + (A2.w + A3.w);

    // combine the 4 q4 partials (partners = lanes differing in threadIdx bits 0-1)
    sx += __shfl_xor(sx, 1, 64);  sx += __shfl_xor(sx, 2, 64);
    sy += __shfl_xor(sy, 1, 64);  sy += __shfl_xor(sy, 2, 64);
    sz += __shfl_xor(sz, 1, 64);  sz += __shfl_xor(sz, 2, 64);
    sw += __shfl_xor(sw, 1, 64);  sw += __shfl_xor(sw, 2, 64);

    if (q4 == 0) {
        float inv = 1.0f / (float)max(deg, 1);
        float4 r;
        r.x = sx * inv; r.y = sy * inv; r.z = sz * inv; r.w = sw * inv;
        *(float4*)(sp + (long long)pass * N * PW + ((long long)n << 3) + (quad << 2)) = r;
    }
}

// ---------- nu1: h1 = relu(agg@Wl1 + bl1 + x@Wr1), all operands LDS-staged; panel output ----------
__global__ __launch_bounds__(256) void nu1_kernel(const float* __restrict__ x,
                                                  const float* __restrict__ s1p,
                                                  const float* __restrict__ Wl,
                                                  const float* __restrict__ bl,
                                                  const float* __restrict__ Wr,
                                                  float* __restrict__ h1p,
                                                  int N) {
    __shared__ float x_sh[STRIP1 * FIN];
    __shared__ float s_sh[STRIP1 * FIN];
    __shared__ float wl_sh[FIN * FIN];
    __shared__ float wr_sh[FIN * FIN];
    __shared__ float bl_sh[FIN];

    int node0 = blockIdx.x * STRIP1;
    if (node0 >= N) return;
    int nn = min(STRIP1, N - node0);
    int tot = nn * FIN;

    for (int t = threadIdx.x; t < FIN * FIN; t += 256) {
        wl_sh[t] = Wl[t];
        wr_sh[t] = Wr[t];
    }
    if (threadIdx.x < FIN) bl_sh[threadIdx.x] = bl[threadIdx.x];
    for (int t = threadIdx.x; t < tot; t += 256) {
        x_sh[t] = x[(long long)node0 * FIN + t];
        int nl = t / FIN;
        int i = t - nl * FIN;
        s_sh[t] = s1p[((long long)(i >> 3) * N + node0 + nl) * PW + (i & 7)];
    }
    __syncthreads();

    for (int t = threadIdx.x; t < tot; t += 256) {
        int nl = t / FIN;
        int j = t - nl * FIN;
        float acc = bl_sh[j];
        #pragma unroll
        for (int i = 0; i < FIN; ++i) {
            acc = fmaf(s_sh[nl * FIN + i], wl_sh[i * FIN + j], acc);
            acc = fmaf(x_sh[nl * FIN + i], wr_sh[i * FIN + j], acc);
        }
        acc = fmaxf(acc, 0.0f);
        h1p[((long long)(j >> 3) * N + node0 + nl) * PW + (j & 7)] = acc;   // panel layout only
    }
}

// ---------- nu2 + pool: h2 = agg@Wl2 + bl2 + h1@Wr2, segment-batched graph max ----------
__global__ __launch_bounds__(128) void nu2_pool_kernel(const float* __restrict__ h1p,
                                                       const float* __restrict__ s2p,
                                                       const float* __restrict__ Wl,
                                                       const float* __restrict__ bl,
                                                       const float* __restrict__ Wr,
                                                       const int* __restrict__ batch,
                                                       unsigned int* __restrict__ genc,
                                                       int N) {
    __shared__ float s_sh[STRIP2 * FIN];
    __shared__ float h_sh[STRIP2 * FIN];
    __shared__ int b_sh[STRIP2];
    int node0 = blockIdx.x * STRIP2;
    if (node0 >= N) return;
    int nn = min(STRIP2, N - node0);
    int tot = nn * FIN;

    for (int t = threadIdx.x; t < tot; t += 128) {
        int nl = t / FIN;
        int i = t - nl * FIN;
        long long pidx = ((long long)(i >> 3) * N + node0 + nl) * PW + (i & 7);
        h_sh[t] = h1p[pidx];
        s_sh[t] = s2p[pidx];
    }
    if (threadIdx.x < nn) b_sh[threadIdx.x] = batch[node0 + threadIdx.x];
    __syncthreads();

    int j = threadIdx.x;
    float wl[FIN], wr[FIN];
    #pragma unroll
    for (int i = 0; i < FIN; ++i) {
        wl[i] = Wl[i * FOUT + j];
        wr[i] = Wr[i * FOUT + j];
    }
    float blj = bl[j];

    int curg = b_sh[0];
    float m = -INFINITY;
    for (int nl = 0; nl < nn; ++nl) {
        float acc = blj;
        #pragma unroll
        for (int i = 0; i < FIN; ++i) {
            acc = fmaf(s_sh[nl * FIN + i], wl[i], acc);
            acc = fmaf(h_sh[nl * FIN + i], wr[i], acc);
        }
        int g = b_sh[nl];   // wave-uniform
        if (g != curg) {
            atomicMax(&genc[curg * FOUT + j], enc_f32(m));
            curg = g;
            m = acc;
        } else {
            m = fmaxf(m, acc);
        }
    }
    atomicMax(&genc[curg * FOUT + j], enc_f32(m));
}

// ---------- head: one block (128 threads) per graph ----------
__global__ void head_kernel(const unsigned int* __restrict__ genc,
                            const float* __restrict__ Wg1, const float* __restrict__ bg1,
                            const float* __restrict__ Wg2, const float* __restrict__ bg2,
                            const float* __restrict__ Wo,  const float* __restrict__ bo,
                            float* __restrict__ out) {
    __shared__ float a[FOUT];
    __shared__ float c[FOUT];
    __shared__ float red[2];
    int g = blockIdx.x;
    int j = threadIdx.x;

    a[j] = dec_f32(genc[g * FOUT + j]);
    __syncthreads();

    float acc = bg1[j];
    #pragma unroll 8
    for (int i = 0; i < FOUT; ++i) acc = fmaf(a[i], Wg1[i * FOUT + j], acc);
    c[j] = fmaxf(acc, 0.0f);
    __syncthreads();

    acc = bg2[j];
    #pragma unroll 8
    for (int i = 0; i < FOUT; ++i) acc = fmaf(c[i], Wg2[i * FOUT + j], acc);
    float t = fmaxf(acc, 0.0f) * Wo[j];

    #pragma unroll
    for (int off = 32; off > 0; off >>= 1) t += __shfl_down(t, off, 64);
    if ((threadIdx.x & 63) == 0) red[threadIdx.x >> 6] = t;
    __syncthreads();
    if (threadIdx.x == 0) out[g] = red[0] + red[1] + bo[0];
}

// ---------- launch ----------
extern "C" void kernel_launch(void* const* d_in, const int* in_sizes, int n_in,
                              void* d_out, int out_size, void* d_ws, size_t ws_size,
                              hipStream_t stream) {
    const float* x    = (const float*)d_in[0];
    const int*   ei   = (const int*)  d_in[1];
    const int*   batch= (const int*)  d_in[2];
    const float* Wl1  = (const float*)d_in[3];
    const float* bl1  = (const float*)d_in[4];
    const float* Wr1  = (const float*)d_in[5];
    const float* Wl2  = (const float*)d_in[6];
    const float* bl2  = (const float*)d_in[7];
    const float* Wr2  = (const float*)d_in[8];
    const float* Wg1  = (const float*)d_in[9];
    const float* bg1  = (const float*)d_in[10];
    const float* Wg2  = (const float*)d_in[11];
    const float* bg2  = (const float*)d_in[12];
    const float* Wo   = (const float*)d_in[13];
    const float* bo   = (const float*)d_in[14];
    float* out = (float*)d_out;

    const int N = in_sizes[0] / FIN;
    const int E = in_sizes[1] / 2;
    const int* src = ei;
    const int* dst = ei + E;

    const int nblk1 = (E + CHUNK - 1) / CHUNK;          // 391
    const int nbuck = (N + 255) >> 8;                   // 391 (<= MAXBUCK)
    const int SC = nbuck * nblk1;                       // 152881
    const int NB2 = (SC + 255) / 256;                   // 598 (<= 1024)

    const size_t panel_elems = (size_t)NP * N * PW;     // 4M floats = 16 MB

    // workspace layout (regionA: ebuf early, h1p later — lifetimes disjoint)
    char* ws = (char*)d_ws;
    size_t off = 0;
    auto alloc = [&](size_t bytes) { char* p = ws + off; off += (bytes + 255) & ~255ull; return p; };
    int*          counts  = (int*)alloc((size_t)SC * 4);
    int*          offs    = (int*)alloc((size_t)(SC + 1) * 4);
    int*          partial = (int*)alloc(1024 * 4);
    int*          row_ptr = (int*)alloc((size_t)(N + 1) * 4);
    int*          esrc    = (int*)alloc((size_t)E * 4);
    char*         regionA = (char*)alloc(panel_elems * 4);       // ebuf (12.8 MB) then h1p (16 MB)
    float*        xp_s2p  = (float*)alloc(panel_elems * 4);      // xp (conv1 in) then s2p (conv2 out)
    float*        s1p     = (float*)alloc(panel_elems * 4);
    unsigned int* genc    = (unsigned int*)alloc((size_t)NGRAPHS * FOUT * 4);
    int*   ebuf = (int*)regionA;
    float* h1p  = (float*)regionA;
    (void)ws_size; (void)n_in; (void)out_size;

    const int BS = 256;
    const int Wtot = NP * N * 8;                         // 40*N items (node x quad x q4)
    int WS = (Wtot / 8 + BS - 1) / BS * BS;              // per-XCD share, 256-aligned
    const int bpx = WS / BS;                             // blocks per XCD share
    const int rpb = (N * NP * PW + BS - 1) / BS;         // repack blocks
    int nu1b = (N + STRIP1 - 1) / STRIP1;
    int nu2b = (N + STRIP2 - 1) / STRIP2;

    // ---- CSR build (LDS radix, no global atomics; reused by both conv layers) ----
    hipLaunchKernelGGL(hist1_kernel, dim3(nblk1), dim3(BS), 0, stream, dst, counts, E, nblk1, nbuck);
    hipLaunchKernelGGL(partial_reduce_kernel, dim3(NB2), dim3(BS), 0, stream, counts, partial, SC);
    hipLaunchKernelGGL(scan_partials_kernel, dim3(1), dim3(1024), 0, stream, partial, NB2);
    hipLaunchKernelGGL(scan_final_kernel, dim3(NB2), dim3(BS), 0, stream, counts, partial, offs, SC);
    hipLaunchKernelGGL(scatter1_kernel, dim3(nblk1), dim3(BS), 0, stream, src, dst, offs, ebuf, E, nblk1, nbuck);
    hipLaunchKernelGGL(csr2_kernel, dim3(nbuck), dim3(BS), 0, stream, ebuf, offs, row_ptr, esrc, E, nblk1, nbuck, N);

    // ---- conv1: repack -> XCD-affinity float4 panel gather -> LDS node update ----
    hipLaunchKernelGGL(repack_kernel, dim3(rpb), dim3(BS), 0, stream, x, xp_s2p, N);
    hipLaunchKernelGGL(gather_panel_kernel, dim3(8 * bpx), dim3(BS), 0, stream,
                       xp_s2p, row_ptr, esrc, s1p, N, Wtot, WS);
    hipLaunchKernelGGL(nu1_kernel, dim3(nu1b), dim3(BS), 0, stream,
                       x, s1p, Wl1, bl1, Wr1, h1p, N);

    // ---- conv2: XCD-affinity float4 panel gather over h1p -> node update + pool ----
    hipLaunchKernelGGL(gather_panel_kernel, dim3(8 * bpx), dim3(BS), 0, stream,
                       h1p, row_ptr, esrc, xp_s2p, N, Wtot, WS);
    hipMemsetAsync(genc, 0, (size_t)NGRAPHS * FOUT * 4, stream);
    hipLaunchKernelGGL(nu2_pool_kernel, dim3(nu2b), dim3(128), 0, stream,
                       h1p, xp_s2p, Wl2, bl2, Wr2, batch, genc, N);

    // ---- head ----
    hipLaunchKernelGGL(head_kernel, dim3(NGRAPHS), dim3(FOUT), 0, stream,
                       genc, Wg1, bg1, Wg2, bg2, Wo, bo, out);
}

// Round 13
// 421.255 us; speedup vs baseline: 1.3750x; 1.1189x over previous
//
#include <hip/hip_runtime.h>
#include <hip/hip_bf16.h>
#include <math.h>

#define FIN 35
#define FOUT 128
#define NGRAPHS 512
#define NP2 3           // fp16 feature panels (ceil(35/16))
#define PW2 16          // panel width (fp16) = 32 B rows
#define STRIP1 32       // nodes per block in nu1
#define STRIP2 16       // nodes per block in nu2
#define CHUNK 8192      // edges per block in hist1/scatter1
#define MAXBUCK 512     // >= ceil(N/256)
#define MAXBE 12288     // csr2 LDS edge-staging capacity (48 KB)

typedef _Float16 half8 __attribute__((ext_vector_type(8)));

// ---------- helpers ----------
__device__ __forceinline__ unsigned int enc_f32(float f) {
    unsigned int u = __float_as_uint(f);
    return (u & 0x80000000u) ? ~u : (u | 0x80000000u);
}
__device__ __forceinline__ float dec_f32(unsigned int u) {
    unsigned int b = (u & 0x80000000u) ? (u ^ 0x80000000u) : ~u;
    return __uint_as_float(b);
}

// ---------- CSR build via two-level LDS radix partition (no global atomics) ----------

__global__ __launch_bounds__(256) void hist1_kernel(const int* __restrict__ dst,
                                                    int* __restrict__ counts,
                                                    int E, int nblk1, int nbuck) {
    __shared__ int h[MAXBUCK];
    for (int t = threadIdx.x; t < nbuck; t += 256) h[t] = 0;
    __syncthreads();
    int base = blockIdx.x * CHUNK;
    int end = min(base + CHUNK, E);
    for (int e = base + threadIdx.x; e < end; e += 256)
        atomicAdd(&h[dst[e] >> 8], 1);
    __syncthreads();
    for (int t = threadIdx.x; t < nbuck; t += 256)
        counts[t * nblk1 + blockIdx.x] = h[t];
}

__global__ void partial_reduce_kernel(const int* __restrict__ v_in, int* __restrict__ partial, int SC) {
    int i = blockIdx.x * 256 + threadIdx.x;
    int v = (i < SC) ? v_in[i] : 0;
    #pragma unroll
    for (int off = 32; off > 0; off >>= 1) v += __shfl_down(v, off, 64);
    __shared__ int w[4];
    if ((threadIdx.x & 63) == 0) w[threadIdx.x >> 6] = v;
    __syncthreads();
    if (threadIdx.x == 0) partial[blockIdx.x] = w[0] + w[1] + w[2] + w[3];
}

__global__ void scan_partials_kernel(int* __restrict__ partial, int NB) {
    __shared__ int lds[1024];
    int t = threadIdx.x;
    int v = (t < NB) ? partial[t] : 0;
    lds[t] = v;
    __syncthreads();
    for (int off = 1; off < 1024; off <<= 1) {
        int tv = (t >= off) ? lds[t - off] : 0;
        __syncthreads();
        lds[t] += tv;
        __syncthreads();
    }
    if (t < NB) partial[t] = lds[t] - v;   // exclusive
}

__global__ void scan_final_kernel(const int* __restrict__ v_in, const int* __restrict__ partial,
                                  int* __restrict__ outx, int SC) {
    __shared__ int lds[256];
    int i = blockIdx.x * 256 + threadIdx.x;
    int v = (i < SC) ? v_in[i] : 0;
    lds[threadIdx.x] = v;
    __syncthreads();
    for (int off = 1; off < 256; off <<= 1) {
        int tv = (threadIdx.x >= off) ? lds[threadIdx.x - off] : 0;
        __syncthreads();
        lds[threadIdx.x] += tv;
        __syncthreads();
    }
    int excl = lds[threadIdx.x] - v + partial[blockIdx.x];
    if (i < SC) {
        outx[i] = excl;
        if (i == SC - 1) outx[SC] = excl + v;
    }
}

__global__ __launch_bounds__(256) void scatter1_kernel(const int* __restrict__ src,
                                                       const int* __restrict__ dst,
                                                       const int* __restrict__ offs,
                                                       int* __restrict__ ebuf,
                                                       int E, int nblk1, int nbuck) {
    __shared__ int cur[MAXBUCK];
    for (int t = threadIdx.x; t < nbuck; t += 256) cur[t] = offs[t * nblk1 + blockIdx.x];
    __syncthreads();
    int base = blockIdx.x * CHUNK;
    int end = min(base + CHUNK, E);
    for (int e = base + threadIdx.x; e < end; e += 256) {
        int d = dst[e];
        int p = atomicAdd(&cur[d >> 8], 1);
        ebuf[p] = (src[e] << 8) | (d & 255);
    }
}

// Level-2: one block per bucket; bucket edges staged in LDS (skips the ebuf re-read).
__global__ __launch_bounds__(256) void csr2_kernel(const int* __restrict__ ebuf,
                                                   const int* __restrict__ offs,
                                                   int* __restrict__ row_ptr,
                                                   int* __restrict__ esrc,
                                                   int E, int nblk1, int nbuck, int N) {
    __shared__ int h[256];
    __shared__ int scn[256];
    __shared__ int e_sh[MAXBE];
    int b = blockIdx.x;
    int t = threadIdx.x;
    int bstart = offs[b * nblk1];
    int bend = (b + 1 < nbuck) ? offs[(b + 1) * nblk1] : E;
    int cnt = bend - bstart;
    bool fit = (cnt <= MAXBE);

    if (fit)
        for (int k = t; k < cnt; k += 256) e_sh[k] = ebuf[bstart + k];
    h[t] = 0;
    __syncthreads();
    for (int k = t; k < cnt; k += 256)
        atomicAdd(&h[(fit ? e_sh[k] : ebuf[bstart + k]) & 255], 1);
    __syncthreads();

    int v = h[t];
    scn[t] = v;
    __syncthreads();
    for (int off = 1; off < 256; off <<= 1) {
        int tv = (t >= off) ? scn[t - off] : 0;
        __syncthreads();
        scn[t] += tv;
        __syncthreads();
    }
    int excl = scn[t] - v;
    int node = (b << 8) + t;
    if (node < N) row_ptr[node] = bstart + excl;
    if (b == 0 && t == 0) row_ptr[N] = E;

    __syncthreads();
    h[t] = bstart + excl;
    __syncthreads();
    for (int k = t; k < cnt; k += 256) {
        int e = fit ? e_sh[k] : ebuf[bstart + k];
        int p = atomicAdd(&h[e & 255], 1);
        esrc[p] = e >> 8;
    }
}

// ---------- repack x[N][35] -> 3 fp16 panels xp[p][N][16] (32 B rows, pad zeroed) ----------
__global__ void repack_kernel(const float* __restrict__ x, _Float16* __restrict__ xp, int N) {
    int t = blockIdx.x * 256 + threadIdx.x;          // < N*48
    if (t >= N * (NP2 * PW2)) return;
    int n = t / (NP2 * PW2);
    int f = t - n * (NP2 * PW2);
    float v = (f < FIN) ? x[(long long)n * FIN + f] : 0.0f;
    xp[((long long)(f >> 4) * N + n) * PW2 + (f & 15)] = (_Float16)v;
}

// ---------- XCD-affinity fp16 panelized gather: 16B lanes + 4-way edge split ----------
// Item = (node, quad, q4): 8 items/node/pass, Wtot = 24N. Same L2-clean geometry as
// round 12 (share window ~6%, one 3.2 MB panel resident/XCD) but passes drop 5->3:
// random line transactions per layer = 3E instead of 5E (the measured ~170 G lines/s
// ceiling is the binding constraint). Lane loads 16 B = 8 fp16 feats; f32 accumulate.
// WS 256-aligned, Wtot 256-divisible, NI=8N 256-divisible -> no wave straddles a pass
// or share cut; shfl groups (lane bits 0-1) always intact.
__global__ __launch_bounds__(256) void gather_panel_kernel(const _Float16* __restrict__ panels,
                                                           const int* __restrict__ row_ptr,
                                                           const int* __restrict__ esrc,
                                                           float* __restrict__ sp,
                                                           int N, int Wtot, int WS) {
    int q = blockIdx.x & 7;
    int m = blockIdx.x >> 3;
    int w = q * WS + m * 256 + threadIdx.x;
    int wend = min((q + 1) * WS, Wtot);
    if (w >= wend) return;
    int NI = N * 8;                          // items per pass
    int pass = w / NI;
    int t = w - pass * NI;
    int n = t >> 3;
    int quad = (t >> 2) & 1;                 // feature half: 0 -> feats 0-7, 1 -> 8-15
    int q4 = t & 3;                          // edge-list quarter
    const _Float16* base = panels + ((long long)pass * N << 4) + (quad << 3);
    int b = row_ptr[n];
    int e = row_ptr[n + 1];
    int deg = e - b;
    int k0 = b + ((deg * q4) >> 2);
    int k1 = b + ((deg * (q4 + 1)) >> 2);

    float a0[8] = {0,0,0,0,0,0,0,0}, a1[8] = {0,0,0,0,0,0,0,0};
    float a2[8] = {0,0,0,0,0,0,0,0}, a3[8] = {0,0,0,0,0,0,0,0};
    int k = k0;
    for (; k + 4 <= k1; k += 4) {
        int s0 = esrc[k], s1 = esrc[k + 1], s2 = esrc[k + 2], s3 = esrc[k + 3];
        half8 v0 = *(const half8*)(base + ((long long)s0 << 4));
        half8 v1 = *(const half8*)(base + ((long long)s1 << 4));
        half8 v2 = *(const half8*)(base + ((long long)s2 << 4));
        half8 v3 = *(const half8*)(base + ((long long)s3 << 4));
        #pragma unroll
        for (int i = 0; i < 8; ++i) {
            a0[i] += (float)v0[i];
            a1[i] += (float)v1[i];
            a2[i] += (float)v2[i];
            a3[i] += (float)v3[i];
        }
    }
    for (; k < k1; ++k) {
        half8 v = *(const half8*)(base + ((long long)esrc[k] << 4));
        #pragma unroll
        for (int i = 0; i < 8; ++i) a0[i] += (float)v[i];
    }

    float s[8];
    #pragma unroll
    for (int i = 0; i < 8; ++i) {
        float p = (a0[i] + a1[i]) + (a2[i] + a3[i]);
        p += __shfl_xor(p, 1, 64);           // combine q4 partials (lane bits 0-1)
        p += __shfl_xor(p, 2, 64);
        s[i] = p;
    }

    if (q4 == 0) {
        float inv = 1.0f / (float)max(deg, 1);
        float* outp = sp + ((long long)pass * N << 4) + ((long long)n << 4) + (quad << 3);
        float4 r0, r1;
        r0.x = s[0] * inv; r0.y = s[1] * inv; r0.z = s[2] * inv; r0.w = s[3] * inv;
        r1.x = s[4] * inv; r1.y = s[5] * inv; r1.z = s[6] * inv; r1.w = s[7] * inv;
        *(float4*)outp = r0;
        *(float4*)(outp + 4) = r1;
    }
}

// ---------- nu1: h1 = relu(agg@Wl1 + bl1 + x@Wr1), LDS-staged; fp16 panel output ----------
__global__ __launch_bounds__(256) void nu1_kernel(const float* __restrict__ x,
                                                  const float* __restrict__ s1p,
                                                  const float* __restrict__ Wl,
                                                  const float* __restrict__ bl,
                                                  const float* __restrict__ Wr,
                                                  _Float16* __restrict__ h1p,
                                                  int N) {
    __shared__ float x_sh[STRIP1 * FIN];
    __shared__ float s_sh[STRIP1 * FIN];
    __shared__ float wl_sh[FIN * FIN];
    __shared__ float wr_sh[FIN * FIN];
    __shared__ float bl_sh[FIN];

    int node0 = blockIdx.x * STRIP1;
    if (node0 >= N) return;
    int nn = min(STRIP1, N - node0);
    int tot = nn * FIN;

    for (int t = threadIdx.x; t < FIN * FIN; t += 256) {
        wl_sh[t] = Wl[t];
        wr_sh[t] = Wr[t];
    }
    if (threadIdx.x < FIN) bl_sh[threadIdx.x] = bl[threadIdx.x];
    for (int t = threadIdx.x; t < tot; t += 256) {
        x_sh[t] = x[(long long)node0 * FIN + t];
        int nl = t / FIN;
        int i = t - nl * FIN;
        s_sh[t] = s1p[((long long)(i >> 4) * N + node0 + nl) * PW2 + (i & 15)];
    }
    __syncthreads();

    for (int t = threadIdx.x; t < tot; t += 256) {
        int nl = t / FIN;
        int j = t - nl * FIN;
        float acc = bl_sh[j];
        #pragma unroll
        for (int i = 0; i < FIN; ++i) {
            acc = fmaf(s_sh[nl * FIN + i], wl_sh[i * FIN + j], acc);
            acc = fmaf(x_sh[nl * FIN + i], wr_sh[i * FIN + j], acc);
        }
        acc = fmaxf(acc, 0.0f);
        h1p[((long long)(j >> 4) * N + node0 + nl) * PW2 + (j & 15)] = (_Float16)acc;
    }
    // note: panel-2 cols 35..47 of h1p stay garbage; gather2 sums them into sp cols
    // that nu2 never reads (i<35). Values are finite (poison = small fp16), harmless.
}

// ---------- nu2 + pool: h2 = agg@Wl2 + bl2 + h1@Wr2, segment-batched graph max ----------
__global__ __launch_bounds__(128) void nu2_pool_kernel(const _Float16* __restrict__ h1p,
                                                       const float* __restrict__ s2p,
                                                       const float* __restrict__ Wl,
                                                       const float* __restrict__ bl,
                                                       const float* __restrict__ Wr,
                                                       const int* __restrict__ batch,
                                                       unsigned int* __restrict__ genc,
                                                       int N) {
    __shared__ float s_sh[STRIP2 * FIN];
    __shared__ float h_sh[STRIP2 * FIN];
    __shared__ int b_sh[STRIP2];
    int node0 = blockIdx.x * STRIP2;
    if (node0 >= N) return;
    int nn = min(STRIP2, N - node0);
    int tot = nn * FIN;

    for (int t = threadIdx.x; t < tot; t += 128) {
        int nl = t / FIN;
        int i = t - nl * FIN;
        long long pidx = ((long long)(i >> 4) * N + node0 + nl) * PW2 + (i & 15);
        h_sh[t] = (float)h1p[pidx];
        s_sh[t] = s2p[pidx];
    }
    if (threadIdx.x < nn) b_sh[threadIdx.x] = batch[node0 + threadIdx.x];
    __syncthreads();

    int j = threadIdx.x;
    float wl[FIN], wr[FIN];
    #pragma unroll
    for (int i = 0; i < FIN; ++i) {
        wl[i] = Wl[i * FOUT + j];
        wr[i] = Wr[i * FOUT + j];
    }
    float blj = bl[j];

    int curg = b_sh[0];
    float m = -INFINITY;
    for (int nl = 0; nl < nn; ++nl) {
        float acc = blj;
        #pragma unroll
        for (int i = 0; i < FIN; ++i) {
            acc = fmaf(s_sh[nl * FIN + i], wl[i], acc);
            acc = fmaf(h_sh[nl * FIN + i], wr[i], acc);
        }
        int g = b_sh[nl];   // wave-uniform
        if (g != curg) {
            atomicMax(&genc[curg * FOUT + j], enc_f32(m));
            curg = g;
            m = acc;
        } else {
            m = fmaxf(m, acc);
        }
    }
    atomicMax(&genc[curg * FOUT + j], enc_f32(m));
}

// ---------- head: one block (128 threads) per graph ----------
__global__ void head_kernel(const unsigned int* __restrict__ genc,
                            const float* __restrict__ Wg1, const float* __restrict__ bg1,
                            const float* __restrict__ Wg2, const float* __restrict__ bg2,
                            const float* __restrict__ Wo,  const float* __restrict__ bo,
                            float* __restrict__ out) {
    __shared__ float a[FOUT];
    __shared__ float c[FOUT];
    __shared__ float red[2];
    int g = blockIdx.x;
    int j = threadIdx.x;

    a[j] = dec_f32(genc[g * FOUT + j]);
    __syncthreads();

    float acc = bg1[j];
    #pragma unroll 8
    for (int i = 0; i < FOUT; ++i) acc = fmaf(a[i], Wg1[i * FOUT + j], acc);
    c[j] = fmaxf(acc, 0.0f);
    __syncthreads();

    acc = bg2[j];
    #pragma unroll 8
    for (int i = 0; i < FOUT; ++i) acc = fmaf(c[i], Wg2[i * FOUT + j], acc);
    float t = fmaxf(acc, 0.0f) * Wo[j];

    #pragma unroll
    for (int off = 32; off > 0; off >>= 1) t += __shfl_down(t, off, 64);
    if ((threadIdx.x & 63) == 0) red[threadIdx.x >> 6] = t;
    __syncthreads();
    if (threadIdx.x == 0) out[g] = red[0] + red[1] + bo[0];
}

// ---------- launch ----------
extern "C" void kernel_launch(void* const* d_in, const int* in_sizes, int n_in,
                              void* d_out, int out_size, void* d_ws, size_t ws_size,
                              hipStream_t stream) {
    const float* x    = (const float*)d_in[0];
    const int*   ei   = (const int*)  d_in[1];
    const int*   batch= (const int*)  d_in[2];
    const float* Wl1  = (const float*)d_in[3];
    const float* bl1  = (const float*)d_in[4];
    const float* Wr1  = (const float*)d_in[5];
    const float* Wl2  = (const float*)d_in[6];
    const float* bl2  = (const float*)d_in[7];
    const float* Wr2  = (const float*)d_in[8];
    const float* Wg1  = (const float*)d_in[9];
    const float* bg1  = (const float*)d_in[10];
    const float* Wg2  = (const float*)d_in[11];
    const float* bg2  = (const float*)d_in[12];
    const float* Wo   = (const float*)d_in[13];
    const float* bo   = (const float*)d_in[14];
    float* out = (float*)d_out;

    const int N = in_sizes[0] / FIN;
    const int E = in_sizes[1] / 2;
    const int* src = ei;
    const int* dst = ei + E;

    const int nblk1 = (E + CHUNK - 1) / CHUNK;          // 391
    const int nbuck = (N + 255) >> 8;                   // 391 (<= MAXBUCK)
    const int SC = nbuck * nblk1;                       // 152881
    const int NB2 = (SC + 255) / 256;                   // 598 (<= 1024)

    const size_t pan16 = (size_t)NP2 * N * PW2;         // 4.8M elems

    // workspace layout (lifetimes: ebuf -> h1p ; xp -> s2p)
    char* ws = (char*)d_ws;
    size_t off = 0;
    auto alloc = [&](size_t bytes) { char* p = ws + off; off += (bytes + 255) & ~255ull; return p; };
    int*          counts  = (int*)alloc((size_t)SC * 4);
    int*          offs    = (int*)alloc((size_t)(SC + 1) * 4);
    int*          partial = (int*)alloc(1024 * 4);
    int*          row_ptr = (int*)alloc((size_t)(N + 1) * 4);
    int*          esrc    = (int*)alloc((size_t)E * 4);
    char*         regionA = (char*)alloc((size_t)E * 4);            // ebuf (12.8 MB) then h1p fp16 (9.6 MB)
    char*         regionB = (char*)alloc(pan16 * 4);                // xp fp16 (9.6 MB) then s2p f32 (19.2 MB)
    float*        s1p     = (float*)alloc(pan16 * 4);               // 19.2 MB
    unsigned int* genc    = (unsigned int*)alloc((size_t)NGRAPHS * FOUT * 4);
    int*       ebuf = (int*)regionA;
    _Float16*  h1p  = (_Float16*)regionA;
    _Float16*  xp   = (_Float16*)regionB;
    float*     s2p  = (float*)regionB;
    (void)ws_size; (void)n_in; (void)out_size;

    const int BS = 256;
    const int Wtot = NP2 * N * 8;                        // 24N items
    int WS = ((Wtot / 8 + BS - 1) / BS) * BS;            // per-XCD share, 256-aligned
    const int bpx = WS / BS;                             // blocks per XCD share
    const int rpb = (N * NP2 * PW2 + BS - 1) / BS;       // repack blocks
    int nu1b = (N + STRIP1 - 1) / STRIP1;
    int nu2b = (N + STRIP2 - 1) / STRIP2;

    // ---- CSR build (LDS radix, no global atomics; reused by both conv layers) ----
    hipLaunchKernelGGL(hist1_kernel, dim3(nblk1), dim3(BS), 0, stream, dst, counts, E, nblk1, nbuck);
    hipLaunchKernelGGL(partial_reduce_kernel, dim3(NB2), dim3(BS), 0, stream, counts, partial, SC);
    hipLaunchKernelGGL(scan_partials_kernel, dim3(1), dim3(1024), 0, stream, partial, NB2);
    hipLaunchKernelGGL(scan_final_kernel, dim3(NB2), dim3(BS), 0, stream, counts, partial, offs, SC);
    hipLaunchKernelGGL(scatter1_kernel, dim3(nblk1), dim3(BS), 0, stream, src, dst, offs, ebuf, E, nblk1, nbuck);
    hipLaunchKernelGGL(csr2_kernel, dim3(nbuck), dim3(BS), 0, stream, ebuf, offs, row_ptr, esrc, E, nblk1, nbuck, N);

    // ---- conv1: fp16 repack -> XCD-affinity panel gather -> LDS node update ----
    hipLaunchKernelGGL(repack_kernel, dim3(rpb), dim3(BS), 0, stream, x, xp, N);
    hipLaunchKernelGGL(gather_panel_kernel, dim3(8 * bpx), dim3(BS), 0, stream,
                       xp, row_ptr, esrc, s1p, N, Wtot, WS);
    hipLaunchKernelGGL(nu1_kernel, dim3(nu1b), dim3(BS), 0, stream,
                       x, s1p, Wl1, bl1, Wr1, h1p, N);

    // ---- conv2: fp16 panel gather over h1p -> node update + pool ----
    hipLaunchKernelGGL(gather_panel_kernel, dim3(8 * bpx), dim3(BS), 0, stream,
                       h1p, row_ptr, esrc, s2p, N, Wtot, WS);
    hipMemsetAsync(genc, 0, (size_t)NGRAPHS * FOUT * 4, stream);
    hipLaunchKernelGGL(nu2_pool_kernel, dim3(nu2b), dim3(128), 0, stream,
                       h1p, s2p, Wl2, bl2, Wr2, batch, genc, N);

    // ---- head ----
    hipLaunchKernelGGL(head_kernel, dim3(NGRAPHS), dim3(FOUT), 0, stream,
                       genc, Wg1, bg1, Wg2, bg2, Wo, bo, out);
}

// Round 14
// 381.070 us; speedup vs baseline: 1.5200x; 1.1055x over previous
//
#include <hip/hip_runtime.h>
#include <hip/hip_bf16.h>
#include <math.h>

#define FIN 35
#define FOUT 128
#define NGRAPHS 512
#define NP2 3           // fp16 feature panels (ceil(35/16))
#define PW2 16          // panel width (fp16) = 32 B rows
#define RP 36           // padded LDS row (floats), 144 B: float4-aligned
#define STRIP1 64       // nodes per block in nu1 (4 waves x 16 nodes)
#define STRIP2 32       // nodes per block in nu2
#define CHUNK 8192      // edges per block in hist1/scatter1
#define MAXBUCK 512     // >= ceil(N/256)
#define MAXBE 12288     // csr2 LDS edge-staging capacity (48 KB)

typedef _Float16 half8 __attribute__((ext_vector_type(8)));

// ---------- helpers ----------
__device__ __forceinline__ unsigned int enc_f32(float f) {
    unsigned int u = __float_as_uint(f);
    return (u & 0x80000000u) ? ~u : (u | 0x80000000u);
}
__device__ __forceinline__ float dec_f32(unsigned int u) {
    unsigned int b = (u & 0x80000000u) ? (u ^ 0x80000000u) : ~u;
    return __uint_as_float(b);
}

// ---------- CSR build via two-level LDS radix partition (no global atomics) ----------

__global__ __launch_bounds__(256) void hist1_kernel(const int* __restrict__ dst,
                                                    int* __restrict__ counts,
                                                    int E, int nblk1, int nbuck) {
    __shared__ int h[MAXBUCK];
    for (int t = threadIdx.x; t < nbuck; t += 256) h[t] = 0;
    __syncthreads();
    int base = blockIdx.x * CHUNK;
    int end = min(base + CHUNK, E);
    for (int e = base + threadIdx.x; e < end; e += 256)
        atomicAdd(&h[dst[e] >> 8], 1);
    __syncthreads();
    for (int t = threadIdx.x; t < nbuck; t += 256)
        counts[t * nblk1 + blockIdx.x] = h[t];
}

__global__ void partial_reduce_kernel(const int* __restrict__ v_in, int* __restrict__ partial, int SC) {
    int i = blockIdx.x * 256 + threadIdx.x;
    int v = (i < SC) ? v_in[i] : 0;
    #pragma unroll
    for (int off = 32; off > 0; off >>= 1) v += __shfl_down(v, off, 64);
    __shared__ int w[4];
    if ((threadIdx.x & 63) == 0) w[threadIdx.x >> 6] = v;
    __syncthreads();
    if (threadIdx.x == 0) partial[blockIdx.x] = w[0] + w[1] + w[2] + w[3];
}

__global__ void scan_partials_kernel(int* __restrict__ partial, int NB) {
    __shared__ int lds[1024];
    int t = threadIdx.x;
    int v = (t < NB) ? partial[t] : 0;
    lds[t] = v;
    __syncthreads();
    for (int off = 1; off < 1024; off <<= 1) {
        int tv = (t >= off) ? lds[t - off] : 0;
        __syncthreads();
        lds[t] += tv;
        __syncthreads();
    }
    if (t < NB) partial[t] = lds[t] - v;   // exclusive
}

__global__ void scan_final_kernel(const int* __restrict__ v_in, const int* __restrict__ partial,
                                  int* __restrict__ outx, int SC) {
    __shared__ int lds[256];
    int i = blockIdx.x * 256 + threadIdx.x;
    int v = (i < SC) ? v_in[i] : 0;
    lds[threadIdx.x] = v;
    __syncthreads();
    for (int off = 1; off < 256; off <<= 1) {
        int tv = (threadIdx.x >= off) ? lds[threadIdx.x - off] : 0;
        __syncthreads();
        lds[threadIdx.x] += tv;
        __syncthreads();
    }
    int excl = lds[threadIdx.x] - v + partial[blockIdx.x];
    if (i < SC) {
        outx[i] = excl;
        if (i == SC - 1) outx[SC] = excl + v;
    }
}

__global__ __launch_bounds__(256) void scatter1_kernel(const int* __restrict__ src,
                                                       const int* __restrict__ dst,
                                                       const int* __restrict__ offs,
                                                       int* __restrict__ ebuf,
                                                       int E, int nblk1, int nbuck) {
    __shared__ int cur[MAXBUCK];
    for (int t = threadIdx.x; t < nbuck; t += 256) cur[t] = offs[t * nblk1 + blockIdx.x];
    __syncthreads();
    int base = blockIdx.x * CHUNK;
    int end = min(base + CHUNK, E);
    for (int e = base + threadIdx.x; e < end; e += 256) {
        int d = dst[e];
        int p = atomicAdd(&cur[d >> 8], 1);
        ebuf[p] = (src[e] << 8) | (d & 255);
    }
}

// Level-2: one block per bucket; bucket edges staged in LDS (skips the ebuf re-read).
__global__ __launch_bounds__(256) void csr2_kernel(const int* __restrict__ ebuf,
                                                   const int* __restrict__ offs,
                                                   int* __restrict__ row_ptr,
                                                   int* __restrict__ esrc,
                                                   int E, int nblk1, int nbuck, int N) {
    __shared__ int h[256];
    __shared__ int scn[256];
    __shared__ int e_sh[MAXBE];
    int b = blockIdx.x;
    int t = threadIdx.x;
    int bstart = offs[b * nblk1];
    int bend = (b + 1 < nbuck) ? offs[(b + 1) * nblk1] : E;
    int cnt = bend - bstart;
    bool fit = (cnt <= MAXBE);

    if (fit)
        for (int k = t; k < cnt; k += 256) e_sh[k] = ebuf[bstart + k];
    h[t] = 0;
    __syncthreads();
    for (int k = t; k < cnt; k += 256)
        atomicAdd(&h[(fit ? e_sh[k] : ebuf[bstart + k]) & 255], 1);
    __syncthreads();

    int v = h[t];
    scn[t] = v;
    __syncthreads();
    for (int off = 1; off < 256; off <<= 1) {
        int tv = (t >= off) ? scn[t - off] : 0;
        __syncthreads();
        scn[t] += tv;
        __syncthreads();
    }
    int excl = scn[t] - v;
    int node = (b << 8) + t;
    if (node < N) row_ptr[node] = bstart + excl;
    if (b == 0 && t == 0) row_ptr[N] = E;

    __syncthreads();
    h[t] = bstart + excl;
    __syncthreads();
    for (int k = t; k < cnt; k += 256) {
        int e = fit ? e_sh[k] : ebuf[bstart + k];
        int p = atomicAdd(&h[e & 255], 1);
        esrc[p] = e >> 8;
    }
}

// ---------- repack x[N][35] -> 3 fp16 panels xp[p][N][16] (32 B rows, pad zeroed) ----------
__global__ void repack_kernel(const float* __restrict__ x, _Float16* __restrict__ xp, int N) {
    int t = blockIdx.x * 256 + threadIdx.x;          // < N*48
    if (t >= N * (NP2 * PW2)) return;
    int n = t / (NP2 * PW2);
    int f = t - n * (NP2 * PW2);
    float v = (f < FIN) ? x[(long long)n * FIN + f] : 0.0f;
    xp[((long long)(f >> 4) * N + n) * PW2 + (f & 15)] = (_Float16)v;
}

// ---------- XCD-affinity fp16 panelized gather: 16B lanes + 4-way edge split ----------
// Item = (node, quad, q4): 8 items/node/pass, Wtot = 24N. L2-clean share geometry
// (one ~3.2 MB panel resident/XCD, passes serialize); 3 passes -> 3E random line
// transactions per layer (the measured ~170 G lines/s ceiling is the binding
// constraint). Lane loads 16 B = 8 fp16 feats; f32 accumulate; shfl combine.
__global__ __launch_bounds__(256) void gather_panel_kernel(const _Float16* __restrict__ panels,
                                                           const int* __restrict__ row_ptr,
                                                           const int* __restrict__ esrc,
                                                           float* __restrict__ sp,
                                                           int N, int Wtot, int WS) {
    int q = blockIdx.x & 7;
    int m = blockIdx.x >> 3;
    int w = q * WS + m * 256 + threadIdx.x;
    int wend = min((q + 1) * WS, Wtot);
    if (w >= wend) return;
    int NI = N * 8;                          // items per pass
    int pass = w / NI;
    int t = w - pass * NI;
    int n = t >> 3;
    int quad = (t >> 2) & 1;                 // feature half: 0 -> feats 0-7, 1 -> 8-15
    int q4 = t & 3;                          // edge-list quarter
    const _Float16* base = panels + ((long long)pass * N << 4) + (quad << 3);
    int b = row_ptr[n];
    int e = row_ptr[n + 1];
    int deg = e - b;
    int k0 = b + ((deg * q4) >> 2);
    int k1 = b + ((deg * (q4 + 1)) >> 2);

    float a0[8] = {0,0,0,0,0,0,0,0}, a1[8] = {0,0,0,0,0,0,0,0};
    float a2[8] = {0,0,0,0,0,0,0,0}, a3[8] = {0,0,0,0,0,0,0,0};
    int k = k0;
    for (; k + 4 <= k1; k += 4) {
        int s0 = esrc[k], s1 = esrc[k + 1], s2 = esrc[k + 2], s3 = esrc[k + 3];
        half8 v0 = *(const half8*)(base + ((long long)s0 << 4));
        half8 v1 = *(const half8*)(base + ((long long)s1 << 4));
        half8 v2 = *(const half8*)(base + ((long long)s2 << 4));
        half8 v3 = *(const half8*)(base + ((long long)s3 << 4));
        #pragma unroll
        for (int i = 0; i < 8; ++i) {
            a0[i] += (float)v0[i];
            a1[i] += (float)v1[i];
            a2[i] += (float)v2[i];
            a3[i] += (float)v3[i];
        }
    }
    for (; k < k1; ++k) {
        half8 v = *(const half8*)(base + ((long long)esrc[k] << 4));
        #pragma unroll
        for (int i = 0; i < 8; ++i) a0[i] += (float)v[i];
    }

    float s[8];
    #pragma unroll
    for (int i = 0; i < 8; ++i) {
        float p = (a0[i] + a1[i]) + (a2[i] + a3[i]);
        p += __shfl_xor(p, 1, 64);           // combine q4 partials (lane bits 0-1)
        p += __shfl_xor(p, 2, 64);
        s[i] = p;
    }

    if (q4 == 0) {
        float inv = 1.0f / (float)max(deg, 1);
        float* outp = sp + ((long long)pass * N << 4) + ((long long)n << 4) + (quad << 3);
        float4 r0, r1;
        r0.x = s[0] * inv; r0.y = s[1] * inv; r0.z = s[2] * inv; r0.w = s[3] * inv;
        r1.x = s[4] * inv; r1.y = s[5] * inv; r1.z = s[6] * inv; r1.w = s[7] * inv;
        *(float4*)outp = r0;
        *(float4*)(outp + 4) = r1;
    }
}

// ---------- nu1: h1 = relu(agg@Wl1 + bl1 + x@Wr1) ----------
// Weights in registers (lane j holds column j), 4 waves x 16 nodes per block,
// float4 broadcast reads from padded (RP=36) LDS rows: ~1 LDS instr per output elem
// instead of 4 (LDS instruction-issue was the limiter).
__global__ __launch_bounds__(256) void nu1_kernel(const float* __restrict__ x,
                                                  const float* __restrict__ s1p,
                                                  const float* __restrict__ Wl,
                                                  const float* __restrict__ bl,
                                                  const float* __restrict__ Wr,
                                                  _Float16* __restrict__ h1p,
                                                  int N) {
    __shared__ float x_sh[STRIP1 * RP];
    __shared__ float s_sh[STRIP1 * RP];

    int node0 = blockIdx.x * STRIP1;
    if (node0 >= N) return;
    int nn = min(STRIP1, N - node0);
    int tot = nn * FIN;

    for (int t = threadIdx.x; t < STRIP1; t += 256) {
        x_sh[t * RP + 35] = 0.0f;
        s_sh[t * RP + 35] = 0.0f;
    }
    for (int t = threadIdx.x; t < tot; t += 256) {
        int nl = t / FIN;
        int i = t - nl * FIN;
        x_sh[nl * RP + i] = x[(long long)node0 * FIN + t];
        s_sh[nl * RP + i] = s1p[((long long)(i >> 4) * N + node0 + nl) * PW2 + (i & 15)];
    }
    __syncthreads();

    int wave = threadIdx.x >> 6;
    int j = threadIdx.x & 63;
    if (j >= FIN) return;                    // no further barriers below

    float wl[36], wr[36];
    #pragma unroll
    for (int i = 0; i < FIN; ++i) {
        wl[i] = Wl[i * FIN + j];
        wr[i] = Wr[i * FIN + j];
    }
    wl[35] = 0.0f; wr[35] = 0.0f;
    float blj = bl[j];

    int nstart = wave * 16;
    int nend = min(nstart + 16, nn);
    for (int nl = nstart; nl < nend; ++nl) {
        float acc = blj;
        #pragma unroll
        for (int c = 0; c < 9; ++c) {
            float4 sv = *(const float4*)&s_sh[nl * RP + 4 * c];
            float4 xv = *(const float4*)&x_sh[nl * RP + 4 * c];
            acc = fmaf(sv.x, wl[4 * c],     acc);
            acc = fmaf(sv.y, wl[4 * c + 1], acc);
            acc = fmaf(sv.z, wl[4 * c + 2], acc);
            acc = fmaf(sv.w, wl[4 * c + 3], acc);
            acc = fmaf(xv.x, wr[4 * c],     acc);
            acc = fmaf(xv.y, wr[4 * c + 1], acc);
            acc = fmaf(xv.z, wr[4 * c + 2], acc);
            acc = fmaf(xv.w, wr[4 * c + 3], acc);
        }
        acc = fmaxf(acc, 0.0f);
        int node = node0 + nl;
        h1p[((long long)(j >> 4) * N + node) * PW2 + (j & 15)] = (_Float16)acc;
    }
    // h1p panel-2 cols 35..47 stay garbage; gather2 sums them into sp cols that
    // nu2 never reads (i<35). Harmless.
}

// ---------- nu2 + pool: h2 = agg@Wl2 + bl2 + h1@Wr2, segment-batched graph max ----------
// float4 broadcast reads from padded rows; weights in registers (as before).
__global__ __launch_bounds__(128) void nu2_pool_kernel(const _Float16* __restrict__ h1p,
                                                       const float* __restrict__ s2p,
                                                       const float* __restrict__ Wl,
                                                       const float* __restrict__ bl,
                                                       const float* __restrict__ Wr,
                                                       const int* __restrict__ batch,
                                                       unsigned int* __restrict__ genc,
                                                       int N) {
    __shared__ float s_sh[STRIP2 * RP];
    __shared__ float h_sh[STRIP2 * RP];
    __shared__ int b_sh[STRIP2];
    int node0 = blockIdx.x * STRIP2;
    if (node0 >= N) return;
    int nn = min(STRIP2, N - node0);
    int tot = nn * FIN;

    for (int t = threadIdx.x; t < STRIP2; t += 128) {
        s_sh[t * RP + 35] = 0.0f;
        h_sh[t * RP + 35] = 0.0f;
    }
    for (int t = threadIdx.x; t < tot; t += 128) {
        int nl = t / FIN;
        int i = t - nl * FIN;
        long long pidx = ((long long)(i >> 4) * N + node0 + nl) * PW2 + (i & 15);
        h_sh[nl * RP + i] = (float)h1p[pidx];
        s_sh[nl * RP + i] = s2p[pidx];
    }
    if (threadIdx.x < nn) b_sh[threadIdx.x] = batch[node0 + threadIdx.x];
    __syncthreads();

    int j = threadIdx.x;
    float wl[36], wr[36];
    #pragma unroll
    for (int i = 0; i < FIN; ++i) {
        wl[i] = Wl[i * FOUT + j];
        wr[i] = Wr[i * FOUT + j];
    }
    wl[35] = 0.0f; wr[35] = 0.0f;
    float blj = bl[j];

    int curg = b_sh[0];
    float m = -INFINITY;
    for (int nl = 0; nl < nn; ++nl) {
        float acc = blj;
        #pragma unroll
        for (int c = 0; c < 9; ++c) {
            float4 sv = *(const float4*)&s_sh[nl * RP + 4 * c];
            float4 hv = *(const float4*)&h_sh[nl * RP + 4 * c];
            acc = fmaf(sv.x, wl[4 * c],     acc);
            acc = fmaf(sv.y, wl[4 * c + 1], acc);
            acc = fmaf(sv.z, wl[4 * c + 2], acc);
            acc = fmaf(sv.w, wl[4 * c + 3], acc);
            acc = fmaf(hv.x, wr[4 * c],     acc);
            acc = fmaf(hv.y, wr[4 * c + 1], acc);
            acc = fmaf(hv.z, wr[4 * c + 2], acc);
            acc = fmaf(hv.w, wr[4 * c + 3], acc);
        }
        int g = b_sh[nl];   // wave-uniform
        if (g != curg) {
            atomicMax(&genc[curg * FOUT + j], enc_f32(m));
            curg = g;
            m = acc;
        } else {
            m = fmaxf(m, acc);
        }
    }
    atomicMax(&genc[curg * FOUT + j], enc_f32(m));
}

// ---------- head: one block (128 threads) per graph ----------
__global__ void head_kernel(const unsigned int* __restrict__ genc,
                            const float* __restrict__ Wg1, const float* __restrict__ bg1,
                            const float* __restrict__ Wg2, const float* __restrict__ bg2,
                            const float* __restrict__ Wo,  const float* __restrict__ bo,
                            float* __restrict__ out) {
    __shared__ float a[FOUT];
    __shared__ float c[FOUT];
    __shared__ float red[2];
    int g = blockIdx.x;
    int j = threadIdx.x;

    a[j] = dec_f32(genc[g * FOUT + j]);
    __syncthreads();

    float acc = bg1[j];
    #pragma unroll 8
    for (int i = 0; i < FOUT; ++i) acc = fmaf(a[i], Wg1[i * FOUT + j], acc);
    c[j] = fmaxf(acc, 0.0f);
    __syncthreads();

    acc = bg2[j];
    #pragma unroll 8
    for (int i = 0; i < FOUT; ++i) acc = fmaf(c[i], Wg2[i * FOUT + j], acc);
    float t = fmaxf(acc, 0.0f) * Wo[j];

    #pragma unroll
    for (int off = 32; off > 0; off >>= 1) t += __shfl_down(t, off, 64);
    if ((threadIdx.x & 63) == 0) red[threadIdx.x >> 6] = t;
    __syncthreads();
    if (threadIdx.x == 0) out[g] = red[0] + red[1] + bo[0];
}

// ---------- launch ----------
extern "C" void kernel_launch(void* const* d_in, const int* in_sizes, int n_in,
                              void* d_out, int out_size, void* d_ws, size_t ws_size,
                              hipStream_t stream) {
    const float* x    = (const float*)d_in[0];
    const int*   ei   = (const int*)  d_in[1];
    const int*   batch= (const int*)  d_in[2];
    const float* Wl1  = (const float*)d_in[3];
    const float* bl1  = (const float*)d_in[4];
    const float* Wr1  = (const float*)d_in[5];
    const float* Wl2  = (const float*)d_in[6];
    const float* bl2  = (const float*)d_in[7];
    const float* Wr2  = (const float*)d_in[8];
    const float* Wg1  = (const float*)d_in[9];
    const float* bg1  = (const float*)d_in[10];
    const float* Wg2  = (const float*)d_in[11];
    const float* bg2  = (const float*)d_in[12];
    const float* Wo   = (const float*)d_in[13];
    const float* bo   = (const float*)d_in[14];
    float* out = (float*)d_out;

    const int N = in_sizes[0] / FIN;
    const int E = in_sizes[1] / 2;
    const int* src = ei;
    const int* dst = ei + E;

    const int nblk1 = (E + CHUNK - 1) / CHUNK;          // 391
    const int nbuck = (N + 255) >> 8;                   // 391 (<= MAXBUCK)
    const int SC = nbuck * nblk1;                       // 152881
    const int NB2 = (SC + 255) / 256;                   // 598 (<= 1024)

    const size_t pan16 = (size_t)NP2 * N * PW2;         // 4.8M elems

    // workspace layout (lifetimes: ebuf -> h1p ; xp -> s2p)
    char* ws = (char*)d_ws;
    size_t off = 0;
    auto alloc = [&](size_t bytes) { char* p = ws + off; off += (bytes + 255) & ~255ull; return p; };
    int*          counts  = (int*)alloc((size_t)SC * 4);
    int*          offs    = (int*)alloc((size_t)(SC + 1) * 4);
    int*          partial = (int*)alloc(1024 * 4);
    int*          row_ptr = (int*)alloc((size_t)(N + 1) * 4);
    int*          esrc    = (int*)alloc((size_t)E * 4);
    char*         regionA = (char*)alloc((size_t)E * 4);            // ebuf (12.8 MB) then h1p fp16 (9.6 MB)
    char*         regionB = (char*)alloc(pan16 * 4);                // xp fp16 (9.6 MB) then s2p f32 (19.2 MB)
    float*        s1p     = (float*)alloc(pan16 * 4);               // 19.2 MB
    unsigned int* genc    = (unsigned int*)alloc((size_t)NGRAPHS * FOUT * 4);
    int*       ebuf = (int*)regionA;
    _Float16*  h1p  = (_Float16*)regionA;
    _Float16*  xp   = (_Float16*)regionB;
    float*     s2p  = (float*)regionB;
    (void)ws_size; (void)n_in; (void)out_size;

    const int BS = 256;
    const int Wtot = NP2 * N * 8;                        // 24N items
    int WS = ((Wtot / 8 + BS - 1) / BS) * BS;            // per-XCD share, 256-aligned
    const int bpx = WS / BS;                             // blocks per XCD share
    const int rpb = (N * NP2 * PW2 + BS - 1) / BS;       // repack blocks
    int nu1b = (N + STRIP1 - 1) / STRIP1;
    int nu2b = (N + STRIP2 - 1) / STRIP2;

    // ---- CSR build (LDS radix, no global atomics; reused by both conv layers) ----
    hipLaunchKernelGGL(hist1_kernel, dim3(nblk1), dim3(BS), 0, stream, dst, counts, E, nblk1, nbuck);
    hipLaunchKernelGGL(partial_reduce_kernel, dim3(NB2), dim3(BS), 0, stream, counts, partial, SC);
    hipLaunchKernelGGL(scan_partials_kernel, dim3(1), dim3(1024), 0, stream, partial, NB2);
    hipLaunchKernelGGL(scan_final_kernel, dim3(NB2), dim3(BS), 0, stream, counts, partial, offs, SC);
    hipLaunchKernelGGL(scatter1_kernel, dim3(nblk1), dim3(BS), 0, stream, src, dst, offs, ebuf, E, nblk1, nbuck);
    hipLaunchKernelGGL(csr2_kernel, dim3(nbuck), dim3(BS), 0, stream, ebuf, offs, row_ptr, esrc, E, nblk1, nbuck, N);

    // ---- conv1: fp16 repack -> XCD-affinity panel gather -> register-weight node update ----
    hipLaunchKernelGGL(repack_kernel, dim3(rpb), dim3(BS), 0, stream, x, xp, N);
    hipLaunchKernelGGL(gather_panel_kernel, dim3(8 * bpx), dim3(BS), 0, stream,
                       xp, row_ptr, esrc, s1p, N, Wtot, WS);
    hipLaunchKernelGGL(nu1_kernel, dim3(nu1b), dim3(BS), 0, stream,
                       x, s1p, Wl1, bl1, Wr1, h1p, N);

    // ---- conv2: fp16 panel gather over h1p -> node update + pool ----
    hipLaunchKernelGGL(gather_panel_kernel, dim3(8 * bpx), dim3(BS), 0, stream,
                       h1p, row_ptr, esrc, s2p, N, Wtot, WS);
    hipMemsetAsync(genc, 0, (size_t)NGRAPHS * FOUT * 4, stream);
    hipLaunchKernelGGL(nu2_pool_kernel, dim3(nu2b), dim3(128), 0, stream,
                       h1p, s2p, Wl2, bl2, Wr2, batch, genc, N);

    // ---- head ----
    hipLaunchKernelGGL(head_kernel, dim3(NGRAPHS), dim3(FOUT), 0, stream,
                       genc, Wg1, bg1, Wg2, bg2, Wo, bo, out);
}